// Round 7
// baseline (138.744 us; speedup 1.0000x reference)
//
#include <hip/hip_runtime.h>
#include <math.h>

// CBAM pillar kernel for MI355X (gfx950) — round 22.
//
// R21 (MFMA layer2, hi/lo bf16 split): 50.7us, MfmaUtil 2.4, VALUBusy 57,
// VGPR 104, LDS 39936 -> 4 blocks/CU pinned by BOTH LDS and VGPR.
// R22 pushes occupancy to 5 blocks/CU + trims VALU:
//  - ybuf processed per 16-ch nt-tile (4 passes) instead of per 32-ch half:
//    buffer 17408 -> 9216 B (per-wave in-order DS makes the reuse safe —
//    empirically validated in R21).  LDS total ~31.6 KB.
//  - mk_frag via v_cvt_pk_bf16_f32 (RNE, bit-identical; ~24 ops vs ~80).
//  - ha/hm chMLP partials split into two j-passes of 8 -> hottest live
//    window loses 16 VGPRs (avg/mxv recomputed per pass, cheap).
//  - host: blocks/CU from numRegs with granule-8 conservative rounding.

#define CO 64

typedef __attribute__((ext_vector_type(8))) short s16x8;
typedef __attribute__((ext_vector_type(4))) float f32x4;
union ABu { uint4 u4; s16x8 s; };

__device__ __forceinline__ float sgm(float x) {
  return 1.0f / (1.0f + __expf(-x));
}
template <int PAT>
__device__ __forceinline__ float qadd(float s) {
  int t = __builtin_amdgcn_update_dpp(0, __builtin_bit_cast(int, s),
                                      PAT, 0xf, 0xf, true);
  return s + __builtin_bit_cast(float, t);
}
template <int PAT>
__device__ __forceinline__ float qmaxd(float m) {
  int t = __builtin_amdgcn_update_dpp(__builtin_bit_cast(int, m),
                                      __builtin_bit_cast(int, m),
                                      PAT, 0xf, 0xf, false);
  return fmaxf(m, __builtin_bit_cast(float, t));
}
template <int PAT>
__device__ __forceinline__ float qmind(float m) {
  int t = __builtin_amdgcn_update_dpp(__builtin_bit_cast(int, m),
                                      __builtin_bit_cast(int, m),
                                      PAT, 0xf, 0xf, false);
  return fminf(m, __builtin_bit_cast(float, t));
}
// full exchange within each 4-lane quad: 0xB1=[1,0,3,2], 0x4E=[2,3,0,1]
__device__ __forceinline__ float qsum4(float s) { return qadd<0x4E>(qadd<0xB1>(s)); }
__device__ __forceinline__ float qmax4(float m) { return qmaxd<0x4E>(qmaxd<0xB1>(m)); }
__device__ __forceinline__ float qmin4(float m) { return qmind<0x4E>(qmind<0xB1>(m)); }
__device__ __forceinline__ void drain_lds() {
  __builtin_amdgcn_wave_barrier();
  __builtin_amdgcn_s_waitcnt(0xC07F);   // lgkmcnt(0)
  __builtin_amdgcn_wave_barrier();
}
__device__ __forceinline__ void drain_vm() {
  __builtin_amdgcn_wave_barrier();
  __builtin_amdgcn_s_waitcnt(0x0F70);   // vmcnt(0)
  __builtin_amdgcn_wave_barrier();
}

// RTN bf16 (RNE) via bit-twiddle — used in once-per-block staging.
__device__ __forceinline__ uint rtn16(float f) {
  uint u = __builtin_bit_cast(uint, f);
  return u + 0x7fffu + ((u >> 16) & 1u);
}
// packed RNE f32->bf16x2 (hw op); lo16 = bf16(a), hi16 = bf16(b)
__device__ __forceinline__ uint cvtpk(float a, float b) {
  uint r;
  asm("v_cvt_pk_bf16_f32 %0, %1, %2" : "=v"(r) : "v"(a), "v"(b));
  return r;
}
// e[8] (k-order) -> hi/lo bf16 fragments; u32[p] packs (e[2p], e[2p+1]).
__device__ __forceinline__ void mk_frag(const float* e, ABu& hi, ABu& lo) {
  uint h[4], l[4];
#pragma unroll
  for (int p = 0; p < 4; ++p) {
    h[p] = cvtpk(e[2 * p], e[2 * p + 1]);
    float d0 = e[2 * p]     - __builtin_bit_cast(float, h[p] << 16);
    float d1 = e[2 * p + 1] - __builtin_bit_cast(float, h[p] & 0xffff0000u);
    l[p] = cvtpk(d0, d1);
  }
  hi.u4 = make_uint4(h[0], h[1], h[2], h[3]);
  lo.u4 = make_uint4(l[0], l[1], l[2], l[3]);
}

// per-voxel: pvox[2p+slot] = {vf[5], bits(bin), 0, 0}  (32B records)
__global__ __launch_bounds__(256) void pack_kernel(
    const float* __restrict__ vf, const int* __restrict__ vcoord,
    const int* __restrict__ unq_inv, float* __restrict__ pvox, int n) {
  int i = blockIdx.x * blockDim.x + threadIdx.x;
  if (i >= n) return;
  int p = unq_inv[i];
  int slot = (i > 0 && unq_inv[i - 1] == p) ? 1 : 0;
  float* dst = pvox + 8 * (size_t)(2 * p + slot);
#pragma unroll
  for (int k = 0; k < 5; ++k) dst[k] = vf[5 * i + k];
  ((int*)dst)[5] = vcoord[4 * i + 1];
}

__global__ __launch_bounds__(256) void cbam_kernel(
    const float* __restrict__ pvox, const int* __restrict__ unq_cnt,
    const float* __restrict__ W1, const float* __restrict__ b1,
    const float* __restrict__ W2, const float* __restrict__ b2,
    const float* __restrict__ Wc1, const float* __restrict__ bc1,
    const float* __restrict__ Wc2, const float* __restrict__ bc2,
    const float* __restrict__ Wsp, const float* __restrict__ bsp,
    float* __restrict__ out, int U, int ngroups, int totalWaves) {
  __shared__ __align__(16) uint4 w2fh[256], w2fl[256];   // W2 bf16 B-frags
  __shared__ __align__(16) float w1b[160], b1b[32];
  __shared__ __align__(16) float wc1b[1024];  // k-major: [(4k+q)*16 + j]
  __shared__ __align__(16) float wc2b[1024];  // k-major Wc2^T
  __shared__ __align__(16) float c0b[64], b2b[64], bc2b[64], bc1b[16];
  __shared__ __align__(16) float wsmx[64];    // float2[32] window sums
  __shared__ __align__(16) float wtab[16];    // float2[8] taps, [7]={0,0}
  __shared__ __align__(16) float vbuf[4][256];   // per-wave voxel block (1KB)
  __shared__ __align__(16) float4 ybuf[4][144];  // per-wave 16 x 9 f4 (one tile)

  const int tid = threadIdx.x;

  // ---- stage weights (once per block; persistent blocks)
  {  // W2 -> bf16 hi/lo B-fragments: tile nt=tid>>6, lane l=tid&63
    const int nt = tid >> 6, l = tid & 63, gg = l >> 4, cc = l & 15;
    uint hu[4], lu[4];
#pragma unroll
    for (int p = 0; p < 4; ++p) {
      float f0 = W2[(8 * gg + 2 * p)     * 64 + 16 * nt + cc];
      float f1 = W2[(8 * gg + 2 * p + 1) * 64 + 16 * nt + cc];
      uint r0 = rtn16(f0), r1 = rtn16(f1);
      hu[p] = (r0 >> 16) | (r1 & 0xffff0000u);
      float d0 = f0 - __builtin_bit_cast(float, r0 & 0xffff0000u);
      float d1 = f1 - __builtin_bit_cast(float, r1 & 0xffff0000u);
      uint s0 = rtn16(d0), s1 = rtn16(d1);
      lu[p] = (s0 >> 16) | (s1 & 0xffff0000u);
    }
    w2fh[tid] = make_uint4(hu[0], hu[1], hu[2], hu[3]);
    w2fl[tid] = make_uint4(lu[0], lu[1], lu[2], lu[3]);
  }
  if (tid < 160) w1b[tid] = W1[tid];
  if (tid < 32) b1b[tid] = b1[tid];
  for (int i = tid; i < 1024; i += 256) {
    // i = ch*16 + j, ch = 16q + k  ->  dst (4k+q)*16 + j
    int ch = i >> 4, j = i & 15, qq = ch >> 4, k = ch & 15;
    wc1b[(4 * k + qq) * 16 + j] = Wc1[i];
    wc2b[(4 * k + qq) * 16 + j] = Wc2[j * 64 + ch];
  }
  if (tid < 64) { b2b[tid] = b2[tid]; bc2b[tid] = bc2[tid]; }
  if (tid < 16) bc1b[tid] = bc1[tid];
  if (tid < 32) {
    float sm = 0.0f, sx = 0.0f;
    for (int k = 0; k < 7; ++k)
      if ((unsigned)(tid + k - 3) < 32u) { sm += Wsp[k]; sx += Wsp[7 + k]; }
    wsmx[2 * tid] = sm; wsmx[2 * tid + 1] = sx;
  }
  if (tid < 8) {
    float a = 0.0f, b = 0.0f;
    if (tid < 7) { a = Wsp[tid]; b = Wsp[7 + tid]; }
    wtab[2 * tid] = a; wtab[2 * tid + 1] = b;
  }
  __syncthreads();
  if (tid < 64) {                      // c0[ch] = b2 + relu(b1) @ W2 (f32)
    float c = b2b[tid];
    for (int j = 0; j < 32; ++j) c += fmaxf(b1b[j], 0.0f) * W2[j * 64 + tid];
    c0b[tid] = c;
  }
  __syncthreads();

  const int wv = tid >> 6, lane = tid & 63;
  int grp = blockIdx.x * 4 + wv;       // static grid-stride schedule
  if (grp >= ngroups) return;          // all __syncthreads are above

  float* const vb = vbuf[wv];
  float4* const vb4 = (float4*)vb;
  float4* const yb4 = ybuf[wv];        // pillar stride 9 float4
  float2* const yb2 = (float2*)yb4;    // pillar stride 18 float2

  const int c16 = lane & 15, g = lane >> 4;   // MFMA lane roles
  const int q = lane & 3, pp = lane >> 2;     // post-processing roles
  const float4* pv4 = (const float4*)pvox;
  const int f4max = 4 * U - 1;         // pvox has 4U float4 entries

  // ---- prologue: async-stage trip-0 voxel block straight to LDS
  {
    int idx = 64 * grp + lane;
    idx = idx < f4max ? idx : f4max;
    __builtin_amdgcn_global_load_lds(
        (const __attribute__((address_space(1))) void*)(pv4 + idx),
        (__attribute__((address_space(3))) void*)vb4, 16, 0, 0);
  }
  drain_vm();

  for (; grp < ngroups; grp += totalWaves) {
    int ofs0 = 0;
    asm volatile("" : "+s"(ofs0));     // keep frag/LDS reads per-trip

    const int P0 = grp * 16;           // 16 pillars this trip

    // ---- metadata (cnt global; bins from current vbuf)
    const int pg = P0 + pp;
    const int pc = pg < U ? pg : (U - 1);
    const int cnt = unq_cnt[pc];
    const int* vbi = (const int*)vb;
    const int b0 = vbi[(2 * pp) * 8 + 5] & 31;
    const int b1raw = vbi[(2 * pp + 1) * 8 + 5];

    // ---- phase 1: per-lane A-fragments.  lane owns rows c16, c16+16,
    // k-chunk 8g..8g+7.  h = relu(b1 + v @ W1), split bf16 hi/lo (RNE).
    ABu ah0, al0, ah1, al1;
    {
      const float4* vb4c = (const float4*)vb;
      float4 xa = vb4c[2 * c16], xb = vb4c[2 * c16 + 1];
      float4 yc = vb4c[2 * (c16 + 16)], yd = vb4c[2 * (c16 + 16) + 1];
      float va[5] = {xa.x, xa.y, xa.z, xa.w, xb.x};
      float vc[5] = {yc.x, yc.y, yc.z, yc.w, yd.x};
      const float4* w1b4 = (const float4*)w1b;
      const float4* b1b4 = (const float4*)b1b;
      float4 bA = b1b4[ofs0 + 2 * g], bB = b1b4[ofs0 + 2 * g + 1];
      float e0[8] = {bA.x, bA.y, bA.z, bA.w, bB.x, bB.y, bB.z, bB.w};
      float e1[8] = {bA.x, bA.y, bA.z, bA.w, bB.x, bB.y, bB.z, bB.w};
#pragma unroll
      for (int d = 0; d < 5; ++d) {
        float4 w0 = w1b4[ofs0 + d * 8 + 2 * g];
        float4 w1v = w1b4[ofs0 + d * 8 + 2 * g + 1];
        e0[0] += va[d] * w0.x;  e0[1] += va[d] * w0.y;
        e0[2] += va[d] * w0.z;  e0[3] += va[d] * w0.w;
        e0[4] += va[d] * w1v.x; e0[5] += va[d] * w1v.y;
        e0[6] += va[d] * w1v.z; e0[7] += va[d] * w1v.w;
        e1[0] += vc[d] * w0.x;  e1[1] += vc[d] * w0.y;
        e1[2] += vc[d] * w0.z;  e1[3] += vc[d] * w0.w;
        e1[4] += vc[d] * w1v.x; e1[5] += vc[d] * w1v.y;
        e1[6] += vc[d] * w1v.z; e1[7] += vc[d] * w1v.w;
      }
#pragma unroll
      for (int i = 0; i < 8; ++i) {
        e0[i] = fmaxf(e0[i], 0.0f);
        e1[i] = fmaxf(e1[i], 0.0f);
      }
      mk_frag(e0, ah0, al0);
      mk_frag(e1, ah1, al1);
    }
    drain_lds();                        // vbuf reads retired before DMA refill

    // ---- vbuf dead: issue next trip's fill straight to LDS
    {
      const int nxt = grp + totalWaves;
      if (nxt < ngroups) {
        int nidx = 64 * nxt + lane;
        nidx = nidx < f4max ? nidx : f4max;
        __builtin_amdgcn_global_load_lds(
            (const __attribute__((address_space(1))) void*)(pv4 + nidx),
            (__attribute__((address_space(3))) void*)vb4, 16, 0, 0);
      }
    }

    // ---- layer2 via MFMA, one 16-ch tile at a time through ybuf.
    // Per-wave in-order DS: write->read->overwrite needs no barriers.
    float y0[16], y1[16];
#pragma unroll
    for (int nt = 0; nt < 4; ++nt) {
      ABu bh, bl;
      bh.u4 = w2fh[ofs0 + nt * 64 + lane];
      bl.u4 = w2fl[ofs0 + nt * 64 + lane];
      f32x4 acc[2];
      acc[0] = 0; acc[1] = 0;
      acc[0] = __builtin_amdgcn_mfma_f32_16x16x32_bf16(ah0.s, bh.s, acc[0], 0, 0, 0);
      acc[0] = __builtin_amdgcn_mfma_f32_16x16x32_bf16(al0.s, bh.s, acc[0], 0, 0, 0);
      acc[0] = __builtin_amdgcn_mfma_f32_16x16x32_bf16(ah0.s, bl.s, acc[0], 0, 0, 0);
      acc[0] = __builtin_amdgcn_mfma_f32_16x16x32_bf16(al0.s, bl.s, acc[0], 0, 0, 0);
      acc[1] = __builtin_amdgcn_mfma_f32_16x16x32_bf16(ah1.s, bh.s, acc[1], 0, 0, 0);
      acc[1] = __builtin_amdgcn_mfma_f32_16x16x32_bf16(al1.s, bh.s, acc[1], 0, 0, 0);
      acc[1] = __builtin_amdgcn_mfma_f32_16x16x32_bf16(ah1.s, bl.s, acc[1], 0, 0, 0);
      acc[1] = __builtin_amdgcn_mfma_f32_16x16x32_bf16(al1.s, bl.s, acc[1], 0, 0, 0);
      // C layout: col=lane&15 (=ch in tile), row=4g+reg; reg pairs (0,1)/
      // (2,3) are the voxel pairs of pillars 8mt+2g / 8mt+2g+1.  +b2 here.
      const float b2v = b2b[16 * nt + c16];
#pragma unroll
      for (int mt = 0; mt < 2; ++mt)
#pragma unroll
        for (int rp = 0; rp < 2; ++rp) {
          const int p = 8 * mt + 2 * g + rp;
          float2 v2;
          v2.x = acc[mt][2 * rp]     + b2v;
          v2.y = acc[mt][2 * rp + 1] + b2v;
          yb2[p * 18 + c16] = v2;
        }
      if (q == nt) {                    // lanes whose 16 ch are this tile
#pragma unroll
        for (int kk = 0; kk < 8; ++kk) {
          float4 t = yb4[pp * 9 + kk];
          y0[2 * kk]     = t.x; y1[2 * kk]     = t.y;
          y0[2 * kk + 1] = t.z; y1[2 * kk + 1] = t.w;
        }
      }
    }

    // ---- post-processing (identical math to R15/R21)
    const bool has2 = (cnt >= 2);
    const int b1e = has2 ? (b1raw & 31) : 64;
#pragma unroll
    for (int k = 0; k < 16; ++k) y1[k] = has2 ? y1[k] : y0[k];

    // chMLP layer1 partials in two j-passes of 8 (VGPR window shrink)
    float gq[16];
    const float kf = has2 ? 30.0f : 31.0f;     // 32 - nocc
    const float inv32 = 1.0f / 32.0f;
    const float4* c04 = (const float4*)c0b;
    const float4* wc14 = (const float4*)wc1b;
    const float4* bc14 = (const float4*)bc1b;
#pragma unroll
    for (int jp = 0; jp < 2; ++jp) {
      float ha[8] = {0}, hm[8] = {0};
#pragma unroll
      for (int kb = 0; kb < 4; ++kb) {
        float4 cq = c04[q * 4 + kb];
        float c0a[4] = {cq.x, cq.y, cq.z, cq.w};
#pragma unroll
        for (int i = 0; i < 4; ++i) {
          const int k = 4 * kb + i;
          const float c0v = c0a[i];
          const float sumy = y0[k] + (has2 ? y1[k] : 0.0f);
          const float avg = fmaf(c0v, kf, sumy) * inv32;
          const float mxv = fmaxf(fmaxf(y0[k], y1[k]), c0v);
#pragma unroll
          for (int jbl = 0; jbl < 2; ++jbl) {
            float4 w = wc14[(4 * k + q) * 4 + 2 * jp + jbl];
            ha[4 * jbl]     += avg * w.x; ha[4 * jbl + 1] += avg * w.y;
            ha[4 * jbl + 2] += avg * w.z; ha[4 * jbl + 3] += avg * w.w;
            hm[4 * jbl]     += mxv * w.x; hm[4 * jbl + 1] += mxv * w.y;
            hm[4 * jbl + 2] += mxv * w.z; hm[4 * jbl + 3] += mxv * w.w;
          }
        }
      }
#pragma unroll
      for (int jbl = 0; jbl < 2; ++jbl) {
        float4 bb = bc14[2 * jp + jbl];
        float bba[4] = {bb.x, bb.y, bb.z, bb.w};
#pragma unroll
        for (int i = 0; i < 4; ++i) {
          const float sa = qsum4(ha[4 * jbl + i]) + bba[i];
          const float sm = qsum4(hm[4 * jbl + i]) + bba[i];
          gq[8 * jp + 4 * jbl + i] = fmaxf(sa, 0.0f) + fmaxf(sm, 0.0f);
        }
      }
    }

    // chMLP layer2 -> attc; bin-column partial reductions
    float attc[16];
    float sc = 0.0f, mc = -3.0e38f;
    float sy0 = 0.0f, my0 = -3.0e38f, sy1 = 0.0f, my1 = -3.0e38f;
    const float4* wc24 = (const float4*)wc2b;
    const float4* bc24 = (const float4*)bc2b;
#pragma unroll
    for (int kb = 0; kb < 4; ++kb) {
      float4 cq = c04[q * 4 + kb];
      float4 bq = bc24[q * 4 + kb];
      float c0a[4] = {cq.x, cq.y, cq.z, cq.w};
      float b2a[4] = {bq.x, bq.y, bq.z, bq.w};
#pragma unroll
      for (int i = 0; i < 4; ++i) {
        const int k = 4 * kb + i;
        float pre = 2.0f * b2a[i];
#pragma unroll
        for (int jb = 0; jb < 4; ++jb) {
          float4 w = wc24[(4 * k + q) * 4 + jb];
          pre += gq[4 * jb] * w.x + gq[4 * jb + 1] * w.y +
                 gq[4 * jb + 2] * w.z + gq[4 * jb + 3] * w.w;
        }
        const float a = sgm(pre);
        attc[k] = a;
        const float pc0 = a * c0a[i], py0 = a * y0[k], py1 = a * y1[k];
        sc += pc0;  mc = fmaxf(mc, pc0);
        sy0 += py0; my0 = fmaxf(my0, py0);
        sy1 += py1; my1 = fmaxf(my1, py1);
      }
    }
    sc = qsum4(sc);   mc = qmax4(mc);
    sy0 = qsum4(sy0); my0 = qmax4(my0);
    sy1 = qsum4(sy1); my1 = qmax4(my1);

    // analytic conv over 32 bins, 8 bins per lane, quad-combined
    const float inv64 = 1.0f / 64.0f;
    const float Mn = sc * inv64, Mx = mc;
    const float dm0 = (sy0 - sc) * inv64, dx0 = my0 - mc;
    const float dm1 = (sy1 - sc) * inv64, dx1 = my1 - mc;
    const float bspr = bsp[0];
    const float2* ws2 = (const float2*)wsmx;
    const float2* wt2 = (const float2*)wtab;
    float maxE = -3.0e38f, minE = 3.0e38f, sv0 = -3.0e38f, sv1 = -3.0e38f;
#pragma unroll
    for (int k = 0; k < 8; ++k) {
      const int b = 8 * q + k;
      float2 ws = ws2[b];
      float acc2 = bspr + Mn * ws.x + Mx * ws.y;
      int k0 = b0 - b + 3;  k0 = ((unsigned)k0 <= 6u) ? k0 : 7;
      int k1 = b1e - b + 3; k1 = ((unsigned)k1 <= 6u) ? k1 : 7;
      float2 w0 = wt2[k0];
      float2 w1v = wt2[k1];
      acc2 += dm0 * w0.x + dx0 * w0.y + dm1 * w1v.x + dx1 * w1v.y;
      const bool o0 = (b == b0), o1 = (b == b1e);
      const bool oc = o0 || o1;
      maxE = fmaxf(maxE, oc ? -3.0e38f : acc2);
      minE = fminf(minE, oc ?  3.0e38f : acc2);
      sv0 = o0 ? acc2 : sv0;
      sv1 = o1 ? acc2 : sv1;
    }
    maxE = qmax4(maxE); minE = qmin4(minE);
    sv0 = qmax4(sv0);   sv1 = qmax4(sv1);
    const float sig0 = sgm(sv0);
    const float sig1 = has2 ? sgm(sv1) : sig0;
    const float sE = sgm(maxE), sI = sgm(minE);

    // epilogue: final max over bins, stores
    if (pg < U) {
      float4* ov = (float4*)(out + (size_t)pg * CO + 16 * q);
#pragma unroll
      for (int kb = 0; kb < 4; ++kb) {
        float4 cq = c04[q * 4 + kb];
        float c0a[4] = {cq.x, cq.y, cq.z, cq.w};
        float rr[4];
#pragma unroll
        for (int i = 0; i < 4; ++i) {
          const int k = 4 * kb + i;
          const float c0v = c0a[i];
          const float sel = (c0v >= 0.0f) ? sE : sI;
          const float m = fmaxf(fmaxf(y0[k] * sig0, y1[k] * sig1), c0v * sel);
          rr[i] = attc[k] * m;
        }
        float4 r; r.x = rr[0]; r.y = rr[1]; r.z = rr[2]; r.w = rr[3];
        ov[kb] = r;
      }
      if (q == 0) out[(size_t)U * CO + pg] = has2 ? 1.0f : 0.0f;
    }

    // ---- next trip's vbuf fill must have landed before reuse
    drain_vm();
  }
}

extern "C" void kernel_launch(void* const* d_in, const int* in_sizes, int n_in,
                              void* d_out, int out_size, void* d_ws, size_t ws_size,
                              hipStream_t stream) {
  const float* vf      = (const float*)d_in[0];
  const int*   vcoord  = (const int*)d_in[1];
  // d_in[2] = unq_coords (unused: identity)
  const int*   unq_inv = (const int*)d_in[3];
  const int*   unq_cnt = (const int*)d_in[4];
  const float* W1  = (const float*)d_in[5];
  const float* b1  = (const float*)d_in[6];
  const float* W2  = (const float*)d_in[7];
  const float* b2  = (const float*)d_in[8];
  const float* Wc1 = (const float*)d_in[9];
  const float* bc1 = (const float*)d_in[10];
  const float* Wc2 = (const float*)d_in[11];
  const float* bc2 = (const float*)d_in[12];
  const float* Wsp = (const float*)d_in[13];
  const float* bsp = (const float*)d_in[14];

  const int N = in_sizes[3];   // voxels
  const int U = in_sizes[4];   // pillars

  float* pvox = (float*)d_ws;  // 2U records x 32B (6.4 MB @ U=100k)

  pack_kernel<<<(N + 255) / 256, 256, 0, stream>>>(vf, vcoord, unq_inv, pvox, N);

  // resident blocks/CU from compiled resources (host-side query, capture-safe).
  // VGPR granule assumed 8 (conservative): waves/SIMD = 512 / round8(numRegs).
  static int blocksPerCU = 0;
  if (blocksPerCU == 0) {
    hipFuncAttributes a{};
    blocksPerCU = 4;
    if (hipFuncGetAttributes(&a, (const void*)cbam_kernel) == hipSuccess) {
      int v8 = (a.numRegs > 0) ? ((a.numRegs + 7) & ~7) : 128;
      int byV = 512 / v8;                                   // waves/SIMD
      int byL = (a.sharedSizeBytes > 0)
                    ? (int)(163840 / (int)a.sharedSizeBytes) : 4;  // blocks/CU
      int m = byV < byL ? byV : byL;
      if (m < 1) m = 1;
      if (m > 8) m = 8;
      blocksPerCU = m;
    }
  }

  const int ngroups = (U + 15) / 16;      // 16 pillars per wave-trip
  int blocks = 256 * blocksPerCU;         // exactly-resident persistent grid
  const int maxBlocks = (ngroups + 3) / 4;
  if (blocks > maxBlocks) blocks = maxBlocks;
  const int totalWaves = blocks * 4;
  cbam_kernel<<<blocks, 256, 0, stream>>>(
      pvox, unq_cnt, W1, b1, W2, b2, Wc1, bc1, Wc2, bc2, Wsp, bsp,
      (float*)d_out, U, ngroups, totalWaves);
}

// Round 9
// 130.661 us; speedup vs baseline: 1.0619x; 1.0619x over previous
//
#include <hip/hip_runtime.h>
#include <math.h>

// CBAM pillar kernel for MI355X (gfx950) — round 24 (= R23 resubmit; the
// R23 bench run died on a container-infrastructure failure, not the kernel).
//
// R21 (MFMA layer2): 50.7us.  R22 (LDS diet): VGPR stuck at 104; occupancy
// steps at 64/128 VGPR -> 4 waves/SIMD is fixed for this kernel; LDS up to
// ~40KB is free.  Remaining: ~140 ds_read_b128 + ~2100 VALU per lane-trip;
// chMLP layer1 alone = ~700 VALU + 64 b128 + 128 DPP ops, and it is
// S[16x64]@Wc1[64x16] twice (avg/max pools) — matmul-shaped.
// R23/24: chMLP-l1 via v_mfma_f32_16x16x32_bf16 (4-term hi/lo split):
//  - Wc1 staged as bf16 B-frags (wc1fh/wc1fl, replaces wc1b, net-0 LDS)
//  - per trip: stats S staged to the (enlarged) per-wave ybuf (sequential
//    reuse, per-wave in-order DS), A-frags read back, 8 MFMA per pool
//  - g = relu(Ga+bc1)+relu(Gm+bc1) bounced through the same buffer to
//    restore (pp,q) layout; chMLP-l2/conv/epilogue untouched.
// LDS 39936 (4 blocks/CU unchanged).

#define CO 64

typedef __attribute__((ext_vector_type(8))) short s16x8;
typedef __attribute__((ext_vector_type(4))) float f32x4;
union ABu { uint4 u4; s16x8 s; };

__device__ __forceinline__ float sgm(float x) {
  return 1.0f / (1.0f + __expf(-x));
}
template <int PAT>
__device__ __forceinline__ float qadd(float s) {
  int t = __builtin_amdgcn_update_dpp(0, __builtin_bit_cast(int, s),
                                      PAT, 0xf, 0xf, true);
  return s + __builtin_bit_cast(float, t);
}
template <int PAT>
__device__ __forceinline__ float qmaxd(float m) {
  int t = __builtin_amdgcn_update_dpp(__builtin_bit_cast(int, m),
                                      __builtin_bit_cast(int, m),
                                      PAT, 0xf, 0xf, false);
  return fmaxf(m, __builtin_bit_cast(float, t));
}
template <int PAT>
__device__ __forceinline__ float qmind(float m) {
  int t = __builtin_amdgcn_update_dpp(__builtin_bit_cast(int, m),
                                      __builtin_bit_cast(int, m),
                                      PAT, 0xf, 0xf, false);
  return fminf(m, __builtin_bit_cast(float, t));
}
// full exchange within each 4-lane quad: 0xB1=[1,0,3,2], 0x4E=[2,3,0,1]
__device__ __forceinline__ float qsum4(float s) { return qadd<0x4E>(qadd<0xB1>(s)); }
__device__ __forceinline__ float qmax4(float m) { return qmaxd<0x4E>(qmaxd<0xB1>(m)); }
__device__ __forceinline__ float qmin4(float m) { return qmind<0x4E>(qmind<0xB1>(m)); }
__device__ __forceinline__ void drain_lds() {
  __builtin_amdgcn_wave_barrier();
  __builtin_amdgcn_s_waitcnt(0xC07F);   // lgkmcnt(0)
  __builtin_amdgcn_wave_barrier();
}
__device__ __forceinline__ void drain_vm() {
  __builtin_amdgcn_wave_barrier();
  __builtin_amdgcn_s_waitcnt(0x0F70);   // vmcnt(0)
  __builtin_amdgcn_wave_barrier();
}

// RTN bf16 (RNE) via bit-twiddle — used in once-per-block staging.
__device__ __forceinline__ uint rtn16(float f) {
  uint u = __builtin_bit_cast(uint, f);
  return u + 0x7fffu + ((u >> 16) & 1u);
}
// packed RNE f32->bf16x2 (hw op); lo16 = bf16(a), hi16 = bf16(b)
__device__ __forceinline__ uint cvtpk(float a, float b) {
  uint r;
  asm("v_cvt_pk_bf16_f32 %0, %1, %2" : "=v"(r) : "v"(a), "v"(b));
  return r;
}
// e[8] (k-order) -> hi/lo bf16 fragments; u32[p] packs (e[2p], e[2p+1]).
__device__ __forceinline__ void mk_frag(const float* e, ABu& hi, ABu& lo) {
  uint h[4], l[4];
#pragma unroll
  for (int p = 0; p < 4; ++p) {
    h[p] = cvtpk(e[2 * p], e[2 * p + 1]);
    float d0 = e[2 * p]     - __builtin_bit_cast(float, h[p] << 16);
    float d1 = e[2 * p + 1] - __builtin_bit_cast(float, h[p] & 0xffff0000u);
    l[p] = cvtpk(d0, d1);
  }
  hi.u4 = make_uint4(h[0], h[1], h[2], h[3]);
  lo.u4 = make_uint4(l[0], l[1], l[2], l[3]);
}

// per-voxel: pvox[2p+slot] = {vf[5], bits(bin), 0, 0}  (32B records)
__global__ __launch_bounds__(256) void pack_kernel(
    const float* __restrict__ vf, const int* __restrict__ vcoord,
    const int* __restrict__ unq_inv, float* __restrict__ pvox, int n) {
  int i = blockIdx.x * blockDim.x + threadIdx.x;
  if (i >= n) return;
  int p = unq_inv[i];
  int slot = (i > 0 && unq_inv[i - 1] == p) ? 1 : 0;
  float* dst = pvox + 8 * (size_t)(2 * p + slot);
#pragma unroll
  for (int k = 0; k < 5; ++k) dst[k] = vf[5 * i + k];
  ((int*)dst)[5] = vcoord[4 * i + 1];
}

__global__ __launch_bounds__(256) void cbam_kernel(
    const float* __restrict__ pvox, const int* __restrict__ unq_cnt,
    const float* __restrict__ W1, const float* __restrict__ b1,
    const float* __restrict__ W2, const float* __restrict__ b2,
    const float* __restrict__ Wc1, const float* __restrict__ bc1,
    const float* __restrict__ Wc2, const float* __restrict__ bc2,
    const float* __restrict__ Wsp, const float* __restrict__ bsp,
    float* __restrict__ out, int U, int ngroups, int totalWaves) {
  __shared__ __align__(16) uint4 w2fh[256], w2fl[256];   // W2 bf16 B-frags
  __shared__ __align__(16) uint4 wc1fh[128], wc1fl[128]; // Wc1 bf16 B-frags
  __shared__ __align__(16) float w1b[160], b1b[32];
  __shared__ __align__(16) float wc2b[1024];  // k-major Wc2^T
  __shared__ __align__(16) float c0b[64], b2b[64], bc2b[64], bc1b[16];
  __shared__ __align__(16) float wsmx[64];    // float2[32] window sums
  __shared__ __align__(16) float wtab[16];    // float2[8] taps, [7]={0,0}
  __shared__ __align__(16) float vbuf[4][256];    // per-wave voxel block (1KB)
  __shared__ __align__(16) float ybuf[4][1088];   // per-wave scratch (4352B):
                                                  // y-transpose / S / g reuse

  const int tid = threadIdx.x;

  // ---- stage weights (once per block; persistent blocks)
  {  // W2 -> bf16 hi/lo B-fragments: tile nt=tid>>6, lane l=tid&63
    const int nt = tid >> 6, l = tid & 63, gg = l >> 4, cc = l & 15;
    uint hu[4], lu[4];
#pragma unroll
    for (int p = 0; p < 4; ++p) {
      float f0 = W2[(8 * gg + 2 * p)     * 64 + 16 * nt + cc];
      float f1 = W2[(8 * gg + 2 * p + 1) * 64 + 16 * nt + cc];
      uint r0 = rtn16(f0), r1 = rtn16(f1);
      hu[p] = (r0 >> 16) | (r1 & 0xffff0000u);
      float d0 = f0 - __builtin_bit_cast(float, r0 & 0xffff0000u);
      float d1 = f1 - __builtin_bit_cast(float, r1 & 0xffff0000u);
      uint s0 = rtn16(d0), s1 = rtn16(d1);
      lu[p] = (s0 >> 16) | (s1 & 0xffff0000u);
    }
    w2fh[tid] = make_uint4(hu[0], hu[1], hu[2], hu[3]);
    w2fl[tid] = make_uint4(lu[0], lu[1], lu[2], lu[3]);
  }
  if (tid < 128) {  // Wc1 -> bf16 hi/lo B-frags, 2 k-steps (ks=tid>>6)
    const int ks = tid >> 6, l = tid & 63, gg = l >> 4, cc = l & 15;
    uint hu[4], lu[4];
#pragma unroll
    for (int p = 0; p < 4; ++p) {
      float f0 = Wc1[(32 * ks + 8 * gg + 2 * p)     * 16 + cc];
      float f1 = Wc1[(32 * ks + 8 * gg + 2 * p + 1) * 16 + cc];
      uint r0 = rtn16(f0), r1 = rtn16(f1);
      hu[p] = (r0 >> 16) | (r1 & 0xffff0000u);
      float d0 = f0 - __builtin_bit_cast(float, r0 & 0xffff0000u);
      float d1 = f1 - __builtin_bit_cast(float, r1 & 0xffff0000u);
      uint s0 = rtn16(d0), s1 = rtn16(d1);
      lu[p] = (s0 >> 16) | (s1 & 0xffff0000u);
    }
    wc1fh[tid] = make_uint4(hu[0], hu[1], hu[2], hu[3]);
    wc1fl[tid] = make_uint4(lu[0], lu[1], lu[2], lu[3]);
  }
  if (tid < 160) w1b[tid] = W1[tid];
  if (tid < 32) b1b[tid] = b1[tid];
  for (int i = tid; i < 1024; i += 256) {
    // i = ch*16 + j, ch = 16q + k  ->  dst (4k+q)*16 + j
    int ch = i >> 4, j = i & 15, qq = ch >> 4, k = ch & 15;
    wc2b[(4 * k + qq) * 16 + j] = Wc2[j * 64 + ch];
  }
  if (tid < 64) { b2b[tid] = b2[tid]; bc2b[tid] = bc2[tid]; }
  if (tid < 16) bc1b[tid] = bc1[tid];
  if (tid < 32) {
    float sm = 0.0f, sx = 0.0f;
    for (int k = 0; k < 7; ++k)
      if ((unsigned)(tid + k - 3) < 32u) { sm += Wsp[k]; sx += Wsp[7 + k]; }
    wsmx[2 * tid] = sm; wsmx[2 * tid + 1] = sx;
  }
  if (tid < 8) {
    float a = 0.0f, b = 0.0f;
    if (tid < 7) { a = Wsp[tid]; b = Wsp[7 + tid]; }
    wtab[2 * tid] = a; wtab[2 * tid + 1] = b;
  }
  __syncthreads();
  if (tid < 64) {                      // c0[ch] = b2 + relu(b1) @ W2 (f32)
    float c = b2b[tid];
    for (int j = 0; j < 32; ++j) c += fmaxf(b1b[j], 0.0f) * W2[j * 64 + tid];
    c0b[tid] = c;
  }
  __syncthreads();

  const int wv = tid >> 6, lane = tid & 63;
  int grp = blockIdx.x * 4 + wv;       // static grid-stride schedule
  if (grp >= ngroups) return;          // all __syncthreads are above

  float* const vb = vbuf[wv];
  float4* const vb4 = (float4*)vb;
  float* const scr = ybuf[wv];         // per-wave scratch
  float4* const yb4 = (float4*)scr;    // y-transpose view (pillar stride 9 f4)
  float2* const yb2 = (float2*)scr;    // pillar stride 18 float2

  const int c16 = lane & 15, g = lane >> 4;   // MFMA lane roles
  const int q = lane & 3, pp = lane >> 2;     // post-processing roles
  const float4* pv4 = (const float4*)pvox;
  const int f4max = 4 * U - 1;         // pvox has 4U float4 entries

  // ---- prologue: async-stage trip-0 voxel block straight to LDS
  {
    int idx = 64 * grp + lane;
    idx = idx < f4max ? idx : f4max;
    __builtin_amdgcn_global_load_lds(
        (const __attribute__((address_space(1))) void*)(pv4 + idx),
        (__attribute__((address_space(3))) void*)vb4, 16, 0, 0);
  }
  drain_vm();

  for (; grp < ngroups; grp += totalWaves) {
    int ofs0 = 0;
    asm volatile("" : "+s"(ofs0));     // keep frag/LDS reads per-trip

    const int P0 = grp * 16;           // 16 pillars this trip

    // ---- metadata (cnt global; bins from current vbuf)
    const int pg = P0 + pp;
    const int pc = pg < U ? pg : (U - 1);
    const int cnt = unq_cnt[pc];
    const int* vbi = (const int*)vb;
    const int b0 = vbi[(2 * pp) * 8 + 5] & 31;
    const int b1raw = vbi[(2 * pp + 1) * 8 + 5];

    // ---- phase 1: per-lane A-fragments.  lane owns rows c16, c16+16,
    // k-chunk 8g..8g+7.  h = relu(b1 + v @ W1), split bf16 hi/lo (RNE).
    ABu ah0, al0, ah1, al1;
    {
      const float4* vb4c = (const float4*)vb;
      float4 xa = vb4c[2 * c16], xb = vb4c[2 * c16 + 1];
      float4 yc = vb4c[2 * (c16 + 16)], yd = vb4c[2 * (c16 + 16) + 1];
      float va[5] = {xa.x, xa.y, xa.z, xa.w, xb.x};
      float vc[5] = {yc.x, yc.y, yc.z, yc.w, yd.x};
      const float4* w1b4 = (const float4*)w1b;
      const float4* b1b4 = (const float4*)b1b;
      float4 bA = b1b4[ofs0 + 2 * g], bB = b1b4[ofs0 + 2 * g + 1];
      float e0[8] = {bA.x, bA.y, bA.z, bA.w, bB.x, bB.y, bB.z, bB.w};
      float e1[8] = {bA.x, bA.y, bA.z, bA.w, bB.x, bB.y, bB.z, bB.w};
#pragma unroll
      for (int d = 0; d < 5; ++d) {
        float4 w0 = w1b4[ofs0 + d * 8 + 2 * g];
        float4 w1v = w1b4[ofs0 + d * 8 + 2 * g + 1];
        e0[0] += va[d] * w0.x;  e0[1] += va[d] * w0.y;
        e0[2] += va[d] * w0.z;  e0[3] += va[d] * w0.w;
        e0[4] += va[d] * w1v.x; e0[5] += va[d] * w1v.y;
        e0[6] += va[d] * w1v.z; e0[7] += va[d] * w1v.w;
        e1[0] += vc[d] * w0.x;  e1[1] += vc[d] * w0.y;
        e1[2] += vc[d] * w0.z;  e1[3] += vc[d] * w0.w;
        e1[4] += vc[d] * w1v.x; e1[5] += vc[d] * w1v.y;
        e1[6] += vc[d] * w1v.z; e1[7] += vc[d] * w1v.w;
      }
#pragma unroll
      for (int i = 0; i < 8; ++i) {
        e0[i] = fmaxf(e0[i], 0.0f);
        e1[i] = fmaxf(e1[i], 0.0f);
      }
      mk_frag(e0, ah0, al0);
      mk_frag(e1, ah1, al1);
    }
    drain_lds();                        // vbuf reads retired before DMA refill

    // ---- vbuf dead: issue next trip's fill straight to LDS
    {
      const int nxt = grp + totalWaves;
      if (nxt < ngroups) {
        int nidx = 64 * nxt + lane;
        nidx = nidx < f4max ? nidx : f4max;
        __builtin_amdgcn_global_load_lds(
            (const __attribute__((address_space(1))) void*)(pv4 + nidx),
            (__attribute__((address_space(3))) void*)vb4, 16, 0, 0);
      }
    }

    // ---- layer2 via MFMA, one 16-ch tile at a time through scr.
    // Per-wave in-order DS: write->read->overwrite needs no barriers.
    float y0[16], y1[16];
#pragma unroll
    for (int nt = 0; nt < 4; ++nt) {
      ABu bh, bl;
      bh.u4 = w2fh[ofs0 + nt * 64 + lane];
      bl.u4 = w2fl[ofs0 + nt * 64 + lane];
      f32x4 acc[2];
      acc[0] = 0; acc[1] = 0;
      acc[0] = __builtin_amdgcn_mfma_f32_16x16x32_bf16(ah0.s, bh.s, acc[0], 0, 0, 0);
      acc[0] = __builtin_amdgcn_mfma_f32_16x16x32_bf16(al0.s, bh.s, acc[0], 0, 0, 0);
      acc[0] = __builtin_amdgcn_mfma_f32_16x16x32_bf16(ah0.s, bl.s, acc[0], 0, 0, 0);
      acc[0] = __builtin_amdgcn_mfma_f32_16x16x32_bf16(al0.s, bl.s, acc[0], 0, 0, 0);
      acc[1] = __builtin_amdgcn_mfma_f32_16x16x32_bf16(ah1.s, bh.s, acc[1], 0, 0, 0);
      acc[1] = __builtin_amdgcn_mfma_f32_16x16x32_bf16(al1.s, bh.s, acc[1], 0, 0, 0);
      acc[1] = __builtin_amdgcn_mfma_f32_16x16x32_bf16(ah1.s, bl.s, acc[1], 0, 0, 0);
      acc[1] = __builtin_amdgcn_mfma_f32_16x16x32_bf16(al1.s, bl.s, acc[1], 0, 0, 0);
      // C layout: col=lane&15 (=ch in tile), row=4g+reg; reg pairs (0,1)/
      // (2,3) are the voxel pairs of pillars 8mt+2g / 8mt+2g+1.  +b2 here.
      const float b2v = b2b[16 * nt + c16];
#pragma unroll
      for (int mt = 0; mt < 2; ++mt)
#pragma unroll
        for (int rp = 0; rp < 2; ++rp) {
          const int p = 8 * mt + 2 * g + rp;
          float2 v2;
          v2.x = acc[mt][2 * rp]     + b2v;
          v2.y = acc[mt][2 * rp + 1] + b2v;
          yb2[p * 18 + c16] = v2;
        }
      if (q == nt) {                    // lanes whose 16 ch are this tile
#pragma unroll
        for (int kk = 0; kk < 8; ++kk) {
          float4 t = yb4[pp * 9 + kk];
          y0[2 * kk]     = t.x; y1[2 * kk]     = t.y;
          y0[2 * kk + 1] = t.z; y1[2 * kk + 1] = t.w;
        }
      }
    }

    const bool has2 = (cnt >= 2);
    const int b1e = has2 ? (b1raw & 31) : 64;
#pragma unroll
    for (int k = 0; k < 16; ++k) y1[k] = has2 ? y1[k] : y0[k];

    // ---- chMLP layer1 via MFMA: G = relu(S@Wc1+bc1) per pool, combined.
    // scr sequentially reused: S_avg -> frags -> S_max -> frags -> g.
    float gq[16];
    {
      const float kf = has2 ? 30.0f : 31.0f;     // 32 - nocc
      const float inv32 = 1.0f / 32.0f;
      const float4* c04 = (const float4*)c0b;
      // stage avg stats: S[p=pp][ch 16q+..] (stride 68 floats)
#pragma unroll
      for (int kb = 0; kb < 4; ++kb) {
        float4 cq = c04[q * 4 + kb];
        float4 t;
        t.x = fmaf(cq.x, kf, y0[4 * kb + 0] + (has2 ? y1[4 * kb + 0] : 0.0f)) * inv32;
        t.y = fmaf(cq.y, kf, y0[4 * kb + 1] + (has2 ? y1[4 * kb + 1] : 0.0f)) * inv32;
        t.z = fmaf(cq.z, kf, y0[4 * kb + 2] + (has2 ? y1[4 * kb + 2] : 0.0f)) * inv32;
        t.w = fmaf(cq.w, kf, y0[4 * kb + 3] + (has2 ? y1[4 * kb + 3] : 0.0f)) * inv32;
        *((float4*)(scr + pp * 68 + 16 * q) + kb) = t;
      }
      // A-frags (avg): row=c16, k=32ks+8g..+7
      ABu ah[2], al[2];
#pragma unroll
      for (int ks = 0; ks < 2; ++ks) {
        const float4* s4 = (const float4*)(scr + c16 * 68 + 32 * ks + 8 * g);
        float4 p0 = s4[0], p1 = s4[1];
        float e[8] = {p0.x, p0.y, p0.z, p0.w, p1.x, p1.y, p1.z, p1.w};
        mk_frag(e, ah[ks], al[ks]);
      }
      f32x4 accA = 0;
#pragma unroll
      for (int ks = 0; ks < 2; ++ks) {
        ABu bh, bl;
        bh.u4 = wc1fh[ofs0 + ks * 64 + lane];
        bl.u4 = wc1fl[ofs0 + ks * 64 + lane];
        accA = __builtin_amdgcn_mfma_f32_16x16x32_bf16(ah[ks].s, bh.s, accA, 0, 0, 0);
        accA = __builtin_amdgcn_mfma_f32_16x16x32_bf16(al[ks].s, bh.s, accA, 0, 0, 0);
        accA = __builtin_amdgcn_mfma_f32_16x16x32_bf16(ah[ks].s, bl.s, accA, 0, 0, 0);
        accA = __builtin_amdgcn_mfma_f32_16x16x32_bf16(al[ks].s, bl.s, accA, 0, 0, 0);
      }
      // stage max stats over the same buffer (in-order DS per wave)
#pragma unroll
      for (int kb = 0; kb < 4; ++kb) {
        float4 cq = c04[q * 4 + kb];
        float4 t;
        t.x = fmaxf(fmaxf(y0[4 * kb + 0], y1[4 * kb + 0]), cq.x);
        t.y = fmaxf(fmaxf(y0[4 * kb + 1], y1[4 * kb + 1]), cq.y);
        t.z = fmaxf(fmaxf(y0[4 * kb + 2], y1[4 * kb + 2]), cq.z);
        t.w = fmaxf(fmaxf(y0[4 * kb + 3], y1[4 * kb + 3]), cq.w);
        *((float4*)(scr + pp * 68 + 16 * q) + kb) = t;
      }
#pragma unroll
      for (int ks = 0; ks < 2; ++ks) {
        const float4* s4 = (const float4*)(scr + c16 * 68 + 32 * ks + 8 * g);
        float4 p0 = s4[0], p1 = s4[1];
        float e[8] = {p0.x, p0.y, p0.z, p0.w, p1.x, p1.y, p1.z, p1.w};
        mk_frag(e, ah[ks], al[ks]);
      }
      f32x4 accM = 0;
#pragma unroll
      for (int ks = 0; ks < 2; ++ks) {
        ABu bh, bl;
        bh.u4 = wc1fh[ofs0 + ks * 64 + lane];
        bl.u4 = wc1fl[ofs0 + ks * 64 + lane];
        accM = __builtin_amdgcn_mfma_f32_16x16x32_bf16(ah[ks].s, bh.s, accM, 0, 0, 0);
        accM = __builtin_amdgcn_mfma_f32_16x16x32_bf16(al[ks].s, bh.s, accM, 0, 0, 0);
        accM = __builtin_amdgcn_mfma_f32_16x16x32_bf16(ah[ks].s, bl.s, accM, 0, 0, 0);
        accM = __builtin_amdgcn_mfma_f32_16x16x32_bf16(al[ks].s, bl.s, accM, 0, 0, 0);
      }
      // g[p][j] = relu(Ga+bc1) + relu(Gm+bc1); lane holds j=c16, p=4g+r.
      // Bounce through scr (stride 20 floats, 16B-aligned rows).
      const float bc1v = bc1b[c16];
#pragma unroll
      for (int r = 0; r < 4; ++r) {
        const float gv = fmaxf(accA[r] + bc1v, 0.0f) +
                         fmaxf(accM[r] + bc1v, 0.0f);
        scr[(4 * g + r) * 20 + c16] = gv;
      }
      const float4* g4 = (const float4*)(scr + pp * 20);
#pragma unroll
      for (int jb = 0; jb < 4; ++jb) {
        float4 t = g4[jb];
        gq[4 * jb] = t.x; gq[4 * jb + 1] = t.y;
        gq[4 * jb + 2] = t.z; gq[4 * jb + 3] = t.w;
      }
    }

    // chMLP layer2 -> attc; bin-column partial reductions
    const float4* c04 = (const float4*)c0b;
    float attc[16];
    float sc = 0.0f, mc = -3.0e38f;
    float sy0 = 0.0f, my0 = -3.0e38f, sy1 = 0.0f, my1 = -3.0e38f;
    const float4* wc24 = (const float4*)wc2b;
    const float4* bc24 = (const float4*)bc2b;
#pragma unroll
    for (int kb = 0; kb < 4; ++kb) {
      float4 cq = c04[q * 4 + kb];
      float4 bq = bc24[q * 4 + kb];
      float c0a[4] = {cq.x, cq.y, cq.z, cq.w};
      float b2a[4] = {bq.x, bq.y, bq.z, bq.w};
#pragma unroll
      for (int i = 0; i < 4; ++i) {
        const int k = 4 * kb + i;
        float pre = 2.0f * b2a[i];
#pragma unroll
        for (int jb = 0; jb < 4; ++jb) {
          float4 w = wc24[(4 * k + q) * 4 + jb];
          pre += gq[4 * jb] * w.x + gq[4 * jb + 1] * w.y +
                 gq[4 * jb + 2] * w.z + gq[4 * jb + 3] * w.w;
        }
        const float a = sgm(pre);
        attc[k] = a;
        const float pc0 = a * c0a[i], py0 = a * y0[k], py1 = a * y1[k];
        sc += pc0;  mc = fmaxf(mc, pc0);
        sy0 += py0; my0 = fmaxf(my0, py0);
        sy1 += py1; my1 = fmaxf(my1, py1);
      }
    }
    sc = qsum4(sc);   mc = qmax4(mc);
    sy0 = qsum4(sy0); my0 = qmax4(my0);
    sy1 = qsum4(sy1); my1 = qmax4(my1);

    // analytic conv over 32 bins, 8 bins per lane, quad-combined
    const float inv64 = 1.0f / 64.0f;
    const float Mn = sc * inv64, Mx = mc;
    const float dm0 = (sy0 - sc) * inv64, dx0 = my0 - mc;
    const float dm1 = (sy1 - sc) * inv64, dx1 = my1 - mc;
    const float bspr = bsp[0];
    const float2* ws2 = (const float2*)wsmx;
    const float2* wt2 = (const float2*)wtab;
    float maxE = -3.0e38f, minE = 3.0e38f, sv0 = -3.0e38f, sv1 = -3.0e38f;
#pragma unroll
    for (int k = 0; k < 8; ++k) {
      const int b = 8 * q + k;
      float2 ws = ws2[b];
      float acc2 = bspr + Mn * ws.x + Mx * ws.y;
      int k0 = b0 - b + 3;  k0 = ((unsigned)k0 <= 6u) ? k0 : 7;
      int k1 = b1e - b + 3; k1 = ((unsigned)k1 <= 6u) ? k1 : 7;
      float2 w0 = wt2[k0];
      float2 w1v = wt2[k1];
      acc2 += dm0 * w0.x + dx0 * w0.y + dm1 * w1v.x + dx1 * w1v.y;
      const bool o0 = (b == b0), o1 = (b == b1e);
      const bool oc = o0 || o1;
      maxE = fmaxf(maxE, oc ? -3.0e38f : acc2);
      minE = fminf(minE, oc ?  3.0e38f : acc2);
      sv0 = o0 ? acc2 : sv0;
      sv1 = o1 ? acc2 : sv1;
    }
    maxE = qmax4(maxE); minE = qmin4(minE);
    sv0 = qmax4(sv0);   sv1 = qmax4(sv1);
    const float sig0 = sgm(sv0);
    const float sig1 = has2 ? sgm(sv1) : sig0;
    const float sE = sgm(maxE), sI = sgm(minE);

    // epilogue: final max over bins, stores
    if (pg < U) {
      float4* ov = (float4*)(out + (size_t)pg * CO + 16 * q);
#pragma unroll
      for (int kb = 0; kb < 4; ++kb) {
        float4 cq = c04[q * 4 + kb];
        float c0a[4] = {cq.x, cq.y, cq.z, cq.w};
        float rr[4];
#pragma unroll
        for (int i = 0; i < 4; ++i) {
          const int k = 4 * kb + i;
          const float c0v = c0a[i];
          const float sel = (c0v >= 0.0f) ? sE : sI;
          const float m = fmaxf(fmaxf(y0[k] * sig0, y1[k] * sig1), c0v * sel);
          rr[i] = attc[k] * m;
        }
        float4 r; r.x = rr[0]; r.y = rr[1]; r.z = rr[2]; r.w = rr[3];
        ov[kb] = r;
      }
      if (q == 0) out[(size_t)U * CO + pg] = has2 ? 1.0f : 0.0f;
    }

    // ---- next trip's vbuf fill must have landed before reuse
    drain_vm();
  }
}

extern "C" void kernel_launch(void* const* d_in, const int* in_sizes, int n_in,
                              void* d_out, int out_size, void* d_ws, size_t ws_size,
                              hipStream_t stream) {
  const float* vf      = (const float*)d_in[0];
  const int*   vcoord  = (const int*)d_in[1];
  // d_in[2] = unq_coords (unused: identity)
  const int*   unq_inv = (const int*)d_in[3];
  const int*   unq_cnt = (const int*)d_in[4];
  const float* W1  = (const float*)d_in[5];
  const float* b1  = (const float*)d_in[6];
  const float* W2  = (const float*)d_in[7];
  const float* b2  = (const float*)d_in[8];
  const float* Wc1 = (const float*)d_in[9];
  const float* bc1 = (const float*)d_in[10];
  const float* Wc2 = (const float*)d_in[11];
  const float* bc2 = (const float*)d_in[12];
  const float* Wsp = (const float*)d_in[13];
  const float* bsp = (const float*)d_in[14];

  const int N = in_sizes[3];   // voxels
  const int U = in_sizes[4];   // pillars

  float* pvox = (float*)d_ws;  // 2U records x 32B (6.4 MB @ U=100k)

  pack_kernel<<<(N + 255) / 256, 256, 0, stream>>>(vf, vcoord, unq_inv, pvox, N);

  // resident blocks/CU from compiled resources (host-side query, capture-safe).
  // Occupancy steps at 64/128/256 VGPR (HW granule).
  static int blocksPerCU = 0;
  if (blocksPerCU == 0) {
    hipFuncAttributes a{};
    blocksPerCU = 4;
    if (hipFuncGetAttributes(&a, (const void*)cbam_kernel) == hipSuccess) {
      int byV = 4;
      if (a.numRegs > 0) {
        if (a.numRegs <= 64) byV = 8;
        else if (a.numRegs <= 128) byV = 4;
        else byV = 2;
      }
      int byL = (a.sharedSizeBytes > 0)
                    ? (int)(163840 / (int)a.sharedSizeBytes) : 4;  // blocks/CU
      int m = byV < byL ? byV : byL;
      if (m < 1) m = 1;
      if (m > 8) m = 8;
      blocksPerCU = m;
    }
  }

  const int ngroups = (U + 15) / 16;      // 16 pillars per wave-trip
  int blocks = 256 * blocksPerCU;         // exactly-resident persistent grid
  const int maxBlocks = (ngroups + 3) / 4;
  if (blocks > maxBlocks) blocks = maxBlocks;
  const int totalWaves = blocks * 4;
  cbam_kernel<<<blocks, 256, 0, stream>>>(
      pvox, unq_cnt, W1, b1, W2, b2, Wc1, bc1, Wc2, bc2, Wsp, bsp,
      (float*)d_out, U, ngroups, totalWaves);
}

// Round 10
// 125.472 us; speedup vs baseline: 1.1058x; 1.0414x over previous
//
#include <hip/hip_runtime.h>
#include <math.h>

// CBAM pillar kernel for MI355X (gfx950) — round 25.
//
// R24 (MFMA layer2 + chMLP-l1): 43.2us, MfmaUtil 4.0, VALUBusy 45, VGPR
// 104.  Occupancy pinned at 4 waves/SIMD (steps at 64/128 VGPR).  VALU
// busy-equiv fell 29->19us R21->R24 while wall fell only 15% -> a ~24us
// latency floor is emerging; keep cutting VALU + shorten MFMA chains.
// R25:
//  - 3-term bf16 split (drop al*bl, ~2^-18 rel): l2y 32->24, l1 16->12
//    MFMAs; acc serial chains 4->3.
//  - chMLP-l2 via MFMA, K=32 stacking: attpre = [relu(Ga+bc1)|relu(Gm+bc1)]
//    @ [Wc2;Wc2].  Stacked-B k-halves identical -> B-frags stored half-
//    width (4KB, exactly replaces wc2b).  Deletes ~140 FMA + 16 b128 wc2
//    reads + gq bounce; adds small ga/gm + attc bounces through scr
//    (same-wave cross-lane LDS, validated R21+) and 12 MFMAs.

#define CO 64

typedef __attribute__((ext_vector_type(8))) short s16x8;
typedef __attribute__((ext_vector_type(4))) float f32x4;
union ABu { uint4 u4; s16x8 s; };

__device__ __forceinline__ float sgm(float x) {
  return 1.0f / (1.0f + __expf(-x));
}
template <int PAT>
__device__ __forceinline__ float qadd(float s) {
  int t = __builtin_amdgcn_update_dpp(0, __builtin_bit_cast(int, s),
                                      PAT, 0xf, 0xf, true);
  return s + __builtin_bit_cast(float, t);
}
template <int PAT>
__device__ __forceinline__ float qmaxd(float m) {
  int t = __builtin_amdgcn_update_dpp(__builtin_bit_cast(int, m),
                                      __builtin_bit_cast(int, m),
                                      PAT, 0xf, 0xf, false);
  return fmaxf(m, __builtin_bit_cast(float, t));
}
template <int PAT>
__device__ __forceinline__ float qmind(float m) {
  int t = __builtin_amdgcn_update_dpp(__builtin_bit_cast(int, m),
                                      __builtin_bit_cast(int, m),
                                      PAT, 0xf, 0xf, false);
  return fminf(m, __builtin_bit_cast(float, t));
}
// full exchange within each 4-lane quad: 0xB1=[1,0,3,2], 0x4E=[2,3,0,1]
__device__ __forceinline__ float qsum4(float s) { return qadd<0x4E>(qadd<0xB1>(s)); }
__device__ __forceinline__ float qmax4(float m) { return qmaxd<0x4E>(qmaxd<0xB1>(m)); }
__device__ __forceinline__ float qmin4(float m) { return qmind<0x4E>(qmind<0xB1>(m)); }
__device__ __forceinline__ void drain_lds() {
  __builtin_amdgcn_wave_barrier();
  __builtin_amdgcn_s_waitcnt(0xC07F);   // lgkmcnt(0)
  __builtin_amdgcn_wave_barrier();
}
__device__ __forceinline__ void drain_vm() {
  __builtin_amdgcn_wave_barrier();
  __builtin_amdgcn_s_waitcnt(0x0F70);   // vmcnt(0)
  __builtin_amdgcn_wave_barrier();
}

// RTN bf16 (RNE) via bit-twiddle — used in once-per-block staging.
__device__ __forceinline__ uint rtn16(float f) {
  uint u = __builtin_bit_cast(uint, f);
  return u + 0x7fffu + ((u >> 16) & 1u);
}
// packed RNE f32->bf16x2 (hw op); lo16 = bf16(a), hi16 = bf16(b)
__device__ __forceinline__ uint cvtpk(float a, float b) {
  uint r;
  asm("v_cvt_pk_bf16_f32 %0, %1, %2" : "=v"(r) : "v"(a), "v"(b));
  return r;
}
// e[8] (k-order) -> hi/lo bf16 fragments; u32[p] packs (e[2p], e[2p+1]).
__device__ __forceinline__ void mk_frag(const float* e, ABu& hi, ABu& lo) {
  uint h[4], l[4];
#pragma unroll
  for (int p = 0; p < 4; ++p) {
    h[p] = cvtpk(e[2 * p], e[2 * p + 1]);
    float d0 = e[2 * p]     - __builtin_bit_cast(float, h[p] << 16);
    float d1 = e[2 * p + 1] - __builtin_bit_cast(float, h[p] & 0xffff0000u);
    l[p] = cvtpk(d0, d1);
  }
  hi.u4 = make_uint4(h[0], h[1], h[2], h[3]);
  lo.u4 = make_uint4(l[0], l[1], l[2], l[3]);
}

// per-voxel: pvox[2p+slot] = {vf[5], bits(bin), 0, 0}  (32B records)
__global__ __launch_bounds__(256) void pack_kernel(
    const float* __restrict__ vf, const int* __restrict__ vcoord,
    const int* __restrict__ unq_inv, float* __restrict__ pvox, int n) {
  int i = blockIdx.x * blockDim.x + threadIdx.x;
  if (i >= n) return;
  int p = unq_inv[i];
  int slot = (i > 0 && unq_inv[i - 1] == p) ? 1 : 0;
  float* dst = pvox + 8 * (size_t)(2 * p + slot);
#pragma unroll
  for (int k = 0; k < 5; ++k) dst[k] = vf[5 * i + k];
  ((int*)dst)[5] = vcoord[4 * i + 1];
}

__global__ __launch_bounds__(256) void cbam_kernel(
    const float* __restrict__ pvox, const int* __restrict__ unq_cnt,
    const float* __restrict__ W1, const float* __restrict__ b1,
    const float* __restrict__ W2, const float* __restrict__ b2,
    const float* __restrict__ Wc1, const float* __restrict__ bc1,
    const float* __restrict__ Wc2, const float* __restrict__ bc2,
    const float* __restrict__ Wsp, const float* __restrict__ bsp,
    float* __restrict__ out, int U, int ngroups, int totalWaves) {
  __shared__ __align__(16) uint4 w2fh[256], w2fl[256];   // W2 bf16 B-frags
  __shared__ __align__(16) uint4 wc1fh[128], wc1fl[128]; // Wc1 bf16 B-frags
  __shared__ __align__(16) uint4 wc2fh[128], wc2fl[128]; // [Wc2;Wc2] B-frags
                                                         // (half-width: g&1)
  __shared__ __align__(16) float w1b[160], b1b[32];
  __shared__ __align__(16) float c0b[64], b2b[64], bc2b[64], bc1b[16];
  __shared__ __align__(16) float wsmx[64];    // float2[32] window sums
  __shared__ __align__(16) float wtab[16];    // float2[8] taps, [7]={0,0}
  __shared__ __align__(16) float vbuf[4][256];    // per-wave voxel block (1KB)
  __shared__ __align__(16) float ybuf[4][1088];   // per-wave scratch (4352B)

  const int tid = threadIdx.x;

  // ---- stage weights (once per block; persistent blocks)
  {  // W2 -> bf16 hi/lo B-fragments: tile nt=tid>>6, lane l=tid&63
    const int nt = tid >> 6, l = tid & 63, gg = l >> 4, cc = l & 15;
    uint hu[4], lu[4];
#pragma unroll
    for (int p = 0; p < 4; ++p) {
      float f0 = W2[(8 * gg + 2 * p)     * 64 + 16 * nt + cc];
      float f1 = W2[(8 * gg + 2 * p + 1) * 64 + 16 * nt + cc];
      uint r0 = rtn16(f0), r1 = rtn16(f1);
      hu[p] = (r0 >> 16) | (r1 & 0xffff0000u);
      float d0 = f0 - __builtin_bit_cast(float, r0 & 0xffff0000u);
      float d1 = f1 - __builtin_bit_cast(float, r1 & 0xffff0000u);
      uint s0 = rtn16(d0), s1 = rtn16(d1);
      lu[p] = (s0 >> 16) | (s1 & 0xffff0000u);
    }
    w2fh[tid] = make_uint4(hu[0], hu[1], hu[2], hu[3]);
    w2fl[tid] = make_uint4(lu[0], lu[1], lu[2], lu[3]);
  }
  if (tid < 128) {  // Wc1 -> bf16 hi/lo B-frags, 2 k-steps (ks=tid>>6)
    const int ks = tid >> 6, l = tid & 63, gg = l >> 4, cc = l & 15;
    uint hu[4], lu[4];
#pragma unroll
    for (int p = 0; p < 4; ++p) {
      float f0 = Wc1[(32 * ks + 8 * gg + 2 * p)     * 16 + cc];
      float f1 = Wc1[(32 * ks + 8 * gg + 2 * p + 1) * 16 + cc];
      uint r0 = rtn16(f0), r1 = rtn16(f1);
      hu[p] = (r0 >> 16) | (r1 & 0xffff0000u);
      float d0 = f0 - __builtin_bit_cast(float, r0 & 0xffff0000u);
      float d1 = f1 - __builtin_bit_cast(float, r1 & 0xffff0000u);
      uint s0 = rtn16(d0), s1 = rtn16(d1);
      lu[p] = (s0 >> 16) | (s1 & 0xffff0000u);
    }
    wc1fh[tid] = make_uint4(hu[0], hu[1], hu[2], hu[3]);
    wc1fl[tid] = make_uint4(lu[0], lu[1], lu[2], lu[3]);
  }
  if (tid < 128) {  // [Wc2;Wc2] B-frags, half-width: idx = nt*32 + g01*16 + cc
    const int nt = tid >> 5, r5 = tid & 31, g01 = r5 >> 4, cc = r5 & 15;
    uint hu[4], lu[4];
#pragma unroll
    for (int p = 0; p < 4; ++p) {
      float f0 = Wc2[(8 * g01 + 2 * p)     * 64 + 16 * nt + cc];
      float f1 = Wc2[(8 * g01 + 2 * p + 1) * 64 + 16 * nt + cc];
      uint r0 = rtn16(f0), r1 = rtn16(f1);
      hu[p] = (r0 >> 16) | (r1 & 0xffff0000u);
      float d0 = f0 - __builtin_bit_cast(float, r0 & 0xffff0000u);
      float d1 = f1 - __builtin_bit_cast(float, r1 & 0xffff0000u);
      uint s0 = rtn16(d0), s1 = rtn16(d1);
      lu[p] = (s0 >> 16) | (s1 & 0xffff0000u);
    }
    wc2fh[tid] = make_uint4(hu[0], hu[1], hu[2], hu[3]);
    wc2fl[tid] = make_uint4(lu[0], lu[1], lu[2], lu[3]);
  }
  if (tid < 160) w1b[tid] = W1[tid];
  if (tid < 32) b1b[tid] = b1[tid];
  if (tid < 64) { b2b[tid] = b2[tid]; bc2b[tid] = bc2[tid]; }
  if (tid < 16) bc1b[tid] = bc1[tid];
  if (tid < 32) {
    float sm = 0.0f, sx = 0.0f;
    for (int k = 0; k < 7; ++k)
      if ((unsigned)(tid + k - 3) < 32u) { sm += Wsp[k]; sx += Wsp[7 + k]; }
    wsmx[2 * tid] = sm; wsmx[2 * tid + 1] = sx;
  }
  if (tid < 8) {
    float a = 0.0f, b = 0.0f;
    if (tid < 7) { a = Wsp[tid]; b = Wsp[7 + tid]; }
    wtab[2 * tid] = a; wtab[2 * tid + 1] = b;
  }
  __syncthreads();
  if (tid < 64) {                      // c0[ch] = b2 + relu(b1) @ W2 (f32)
    float c = b2b[tid];
    for (int j = 0; j < 32; ++j) c += fmaxf(b1b[j], 0.0f) * W2[j * 64 + tid];
    c0b[tid] = c;
  }
  __syncthreads();

  const int wv = tid >> 6, lane = tid & 63;
  int grp = blockIdx.x * 4 + wv;       // static grid-stride schedule
  if (grp >= ngroups) return;          // all __syncthreads are above

  float* const vb = vbuf[wv];
  float4* const vb4 = (float4*)vb;
  float* const scr = ybuf[wv];         // per-wave scratch
  float4* const yb4 = (float4*)scr;    // y-transpose view (pillar stride 9 f4)
  float2* const yb2 = (float2*)scr;    // pillar stride 18 float2

  const int c16 = lane & 15, g = lane >> 4;   // MFMA lane roles
  const int q = lane & 3, pp = lane >> 2;     // post-processing roles
  const float4* pv4 = (const float4*)pvox;
  const int f4max = 4 * U - 1;         // pvox has 4U float4 entries

  // ---- prologue: async-stage trip-0 voxel block straight to LDS
  {
    int idx = 64 * grp + lane;
    idx = idx < f4max ? idx : f4max;
    __builtin_amdgcn_global_load_lds(
        (const __attribute__((address_space(1))) void*)(pv4 + idx),
        (__attribute__((address_space(3))) void*)vb4, 16, 0, 0);
  }
  drain_vm();

  for (; grp < ngroups; grp += totalWaves) {
    int ofs0 = 0;
    asm volatile("" : "+s"(ofs0));     // keep frag/LDS reads per-trip

    const int P0 = grp * 16;           // 16 pillars this trip

    // ---- metadata (cnt global; bins from current vbuf)
    const int pg = P0 + pp;
    const int pc = pg < U ? pg : (U - 1);
    const int cnt = unq_cnt[pc];
    const int* vbi = (const int*)vb;
    const int b0 = vbi[(2 * pp) * 8 + 5] & 31;
    const int b1raw = vbi[(2 * pp + 1) * 8 + 5];

    // ---- phase 1: per-lane A-fragments.  lane owns rows c16, c16+16,
    // k-chunk 8g..8g+7.  h = relu(b1 + v @ W1), split bf16 hi/lo (RNE).
    ABu ah0, al0, ah1, al1;
    {
      const float4* vb4c = (const float4*)vb;
      float4 xa = vb4c[2 * c16], xb = vb4c[2 * c16 + 1];
      float4 yc = vb4c[2 * (c16 + 16)], yd = vb4c[2 * (c16 + 16) + 1];
      float va[5] = {xa.x, xa.y, xa.z, xa.w, xb.x};
      float vc[5] = {yc.x, yc.y, yc.z, yc.w, yd.x};
      const float4* w1b4 = (const float4*)w1b;
      const float4* b1b4 = (const float4*)b1b;
      float4 bA = b1b4[ofs0 + 2 * g], bB = b1b4[ofs0 + 2 * g + 1];
      float e0[8] = {bA.x, bA.y, bA.z, bA.w, bB.x, bB.y, bB.z, bB.w};
      float e1[8] = {bA.x, bA.y, bA.z, bA.w, bB.x, bB.y, bB.z, bB.w};
#pragma unroll
      for (int d = 0; d < 5; ++d) {
        float4 w0 = w1b4[ofs0 + d * 8 + 2 * g];
        float4 w1v = w1b4[ofs0 + d * 8 + 2 * g + 1];
        e0[0] += va[d] * w0.x;  e0[1] += va[d] * w0.y;
        e0[2] += va[d] * w0.z;  e0[3] += va[d] * w0.w;
        e0[4] += va[d] * w1v.x; e0[5] += va[d] * w1v.y;
        e0[6] += va[d] * w1v.z; e0[7] += va[d] * w1v.w;
        e1[0] += vc[d] * w0.x;  e1[1] += vc[d] * w0.y;
        e1[2] += vc[d] * w0.z;  e1[3] += vc[d] * w0.w;
        e1[4] += vc[d] * w1v.x; e1[5] += vc[d] * w1v.y;
        e1[6] += vc[d] * w1v.z; e1[7] += vc[d] * w1v.w;
      }
#pragma unroll
      for (int i = 0; i < 8; ++i) {
        e0[i] = fmaxf(e0[i], 0.0f);
        e1[i] = fmaxf(e1[i], 0.0f);
      }
      mk_frag(e0, ah0, al0);
      mk_frag(e1, ah1, al1);
    }
    drain_lds();                        // vbuf reads retired before DMA refill

    // ---- vbuf dead: issue next trip's fill straight to LDS
    {
      const int nxt = grp + totalWaves;
      if (nxt < ngroups) {
        int nidx = 64 * nxt + lane;
        nidx = nidx < f4max ? nidx : f4max;
        __builtin_amdgcn_global_load_lds(
            (const __attribute__((address_space(1))) void*)(pv4 + nidx),
            (__attribute__((address_space(3))) void*)vb4, 16, 0, 0);
      }
    }

    // ---- layer2 via MFMA (3-term), one 16-ch tile at a time through scr.
    float y0[16], y1[16];
#pragma unroll
    for (int nt = 0; nt < 4; ++nt) {
      ABu bh, bl;
      bh.u4 = w2fh[ofs0 + nt * 64 + lane];
      bl.u4 = w2fl[ofs0 + nt * 64 + lane];
      f32x4 acc[2];
      acc[0] = 0; acc[1] = 0;
      acc[0] = __builtin_amdgcn_mfma_f32_16x16x32_bf16(ah0.s, bh.s, acc[0], 0, 0, 0);
      acc[0] = __builtin_amdgcn_mfma_f32_16x16x32_bf16(al0.s, bh.s, acc[0], 0, 0, 0);
      acc[0] = __builtin_amdgcn_mfma_f32_16x16x32_bf16(ah0.s, bl.s, acc[0], 0, 0, 0);
      acc[1] = __builtin_amdgcn_mfma_f32_16x16x32_bf16(ah1.s, bh.s, acc[1], 0, 0, 0);
      acc[1] = __builtin_amdgcn_mfma_f32_16x16x32_bf16(al1.s, bh.s, acc[1], 0, 0, 0);
      acc[1] = __builtin_amdgcn_mfma_f32_16x16x32_bf16(ah1.s, bl.s, acc[1], 0, 0, 0);
      // C layout: col=lane&15 (=ch in tile), row=4g+reg; reg pairs (0,1)/
      // (2,3) are the voxel pairs of pillars 8mt+2g / 8mt+2g+1.  +b2 here.
      const float b2v = b2b[16 * nt + c16];
#pragma unroll
      for (int mt = 0; mt < 2; ++mt)
#pragma unroll
        for (int rp = 0; rp < 2; ++rp) {
          const int p = 8 * mt + 2 * g + rp;
          float2 v2;
          v2.x = acc[mt][2 * rp]     + b2v;
          v2.y = acc[mt][2 * rp + 1] + b2v;
          yb2[p * 18 + c16] = v2;
        }
      if (q == nt) {                    // lanes whose 16 ch are this tile
#pragma unroll
        for (int kk = 0; kk < 8; ++kk) {
          float4 t = yb4[pp * 9 + kk];
          y0[2 * kk]     = t.x; y1[2 * kk]     = t.y;
          y0[2 * kk + 1] = t.z; y1[2 * kk + 1] = t.w;
        }
      }
    }

    const bool has2 = (cnt >= 2);
    const int b1e = has2 ? (b1raw & 31) : 64;
#pragma unroll
    for (int k = 0; k < 16; ++k) y1[k] = has2 ? y1[k] : y0[k];

    // ---- chMLP l1 via MFMA (3-term): Ga = Sa@Wc1, Gm = Sm@Wc1.
    // scr sequentially reused: S_avg -> frags -> S_max -> frags.
    f32x4 accA = 0, accM = 0;
    {
      const float kf = has2 ? 30.0f : 31.0f;     // 32 - nocc
      const float inv32 = 1.0f / 32.0f;
      const float4* c04 = (const float4*)c0b;
      // stage avg stats: S[p=pp][ch 16q+..] (stride 68 floats)
#pragma unroll
      for (int kb = 0; kb < 4; ++kb) {
        float4 cq = c04[q * 4 + kb];
        float4 t;
        t.x = fmaf(cq.x, kf, y0[4 * kb + 0] + (has2 ? y1[4 * kb + 0] : 0.0f)) * inv32;
        t.y = fmaf(cq.y, kf, y0[4 * kb + 1] + (has2 ? y1[4 * kb + 1] : 0.0f)) * inv32;
        t.z = fmaf(cq.z, kf, y0[4 * kb + 2] + (has2 ? y1[4 * kb + 2] : 0.0f)) * inv32;
        t.w = fmaf(cq.w, kf, y0[4 * kb + 3] + (has2 ? y1[4 * kb + 3] : 0.0f)) * inv32;
        *((float4*)(scr + pp * 68 + 16 * q) + kb) = t;
      }
      ABu ah[2], al[2];
#pragma unroll
      for (int ks = 0; ks < 2; ++ks) {
        const float4* s4 = (const float4*)(scr + c16 * 68 + 32 * ks + 8 * g);
        float4 p0 = s4[0], p1 = s4[1];
        float e[8] = {p0.x, p0.y, p0.z, p0.w, p1.x, p1.y, p1.z, p1.w};
        mk_frag(e, ah[ks], al[ks]);
      }
#pragma unroll
      for (int ks = 0; ks < 2; ++ks) {
        ABu bh, bl;
        bh.u4 = wc1fh[ofs0 + ks * 64 + lane];
        bl.u4 = wc1fl[ofs0 + ks * 64 + lane];
        accA = __builtin_amdgcn_mfma_f32_16x16x32_bf16(ah[ks].s, bh.s, accA, 0, 0, 0);
        accA = __builtin_amdgcn_mfma_f32_16x16x32_bf16(al[ks].s, bh.s, accA, 0, 0, 0);
        accA = __builtin_amdgcn_mfma_f32_16x16x32_bf16(ah[ks].s, bl.s, accA, 0, 0, 0);
      }
      // stage max stats over the same buffer (in-order DS per wave)
#pragma unroll
      for (int kb = 0; kb < 4; ++kb) {
        float4 cq = c04[q * 4 + kb];
        float4 t;
        t.x = fmaxf(fmaxf(y0[4 * kb + 0], y1[4 * kb + 0]), cq.x);
        t.y = fmaxf(fmaxf(y0[4 * kb + 1], y1[4 * kb + 1]), cq.y);
        t.z = fmaxf(fmaxf(y0[4 * kb + 2], y1[4 * kb + 2]), cq.z);
        t.w = fmaxf(fmaxf(y0[4 * kb + 3], y1[4 * kb + 3]), cq.w);
        *((float4*)(scr + pp * 68 + 16 * q) + kb) = t;
      }
#pragma unroll
      for (int ks = 0; ks < 2; ++ks) {
        const float4* s4 = (const float4*)(scr + c16 * 68 + 32 * ks + 8 * g);
        float4 p0 = s4[0], p1 = s4[1];
        float e[8] = {p0.x, p0.y, p0.z, p0.w, p1.x, p1.y, p1.z, p1.w};
        mk_frag(e, ah[ks], al[ks]);
      }
#pragma unroll
      for (int ks = 0; ks < 2; ++ks) {
        ABu bh, bl;
        bh.u4 = wc1fh[ofs0 + ks * 64 + lane];
        bl.u4 = wc1fl[ofs0 + ks * 64 + lane];
        accM = __builtin_amdgcn_mfma_f32_16x16x32_bf16(ah[ks].s, bh.s, accM, 0, 0, 0);
        accM = __builtin_amdgcn_mfma_f32_16x16x32_bf16(al[ks].s, bh.s, accM, 0, 0, 0);
        accM = __builtin_amdgcn_mfma_f32_16x16x32_bf16(ah[ks].s, bl.s, accM, 0, 0, 0);
      }
    }

    // ---- chMLP l2 via MFMA: attpre = [relu(Ga+bc1)|relu(Gm+bc1)] @ [Wc2;Wc2]
    float attc[16];
    {
      // write relu'd pools: row=pillar (stride 36), cols 0..15=ga, 16..31=gm
      const float bc1v = bc1b[c16];
#pragma unroll
      for (int r = 0; r < 4; ++r) {
        scr[(4 * g + r) * 36 + c16]      = fmaxf(accA[r] + bc1v, 0.0f);
        scr[(4 * g + r) * 36 + 16 + c16] = fmaxf(accM[r] + bc1v, 0.0f);
      }
      // A2-frag: lane row=c16 (pillar), k-chunk 8g..8g+7 of the 32-wide row
      ABu a2h, a2l;
      {
        const float4* s4 = (const float4*)(scr + c16 * 36 + 8 * g);
        float4 p0 = s4[0], p1 = s4[1];
        float e[8] = {p0.x, p0.y, p0.z, p0.w, p1.x, p1.y, p1.z, p1.w};
        mk_frag(e, a2h, a2l);
      }
      // 4 output tiles, 3-term; B-frag half-width (g pairs share)
      f32x4 acc2[4];
#pragma unroll
      for (int nt = 0; nt < 4; ++nt) {
        ABu bh, bl;
        bh.u4 = wc2fh[ofs0 + nt * 32 + (g & 1) * 16 + c16];
        bl.u4 = wc2fl[ofs0 + nt * 32 + (g & 1) * 16 + c16];
        f32x4 a = 0;
        a = __builtin_amdgcn_mfma_f32_16x16x32_bf16(a2h.s, bh.s, a, 0, 0, 0);
        a = __builtin_amdgcn_mfma_f32_16x16x32_bf16(a2l.s, bh.s, a, 0, 0, 0);
        a = __builtin_amdgcn_mfma_f32_16x16x32_bf16(a2h.s, bl.s, a, 0, 0, 0);
        acc2[nt] = a;
      }
      // sigmoid in C layout; bounce to (pp,q) layout (stride 68)
#pragma unroll
      for (int nt = 0; nt < 4; ++nt) {
        const float b2c = 2.0f * bc2b[16 * nt + c16];
#pragma unroll
        for (int r = 0; r < 4; ++r)
          scr[(4 * g + r) * 68 + 16 * nt + c16] = sgm(acc2[nt][r] + b2c);
      }
      const float4* a4 = (const float4*)(scr + pp * 68 + 16 * q);
#pragma unroll
      for (int kb = 0; kb < 4; ++kb) {
        float4 t = a4[kb];
        attc[4 * kb] = t.x; attc[4 * kb + 1] = t.y;
        attc[4 * kb + 2] = t.z; attc[4 * kb + 3] = t.w;
      }
    }

    // ---- bin-column partial reductions (products with attc)
    const float4* c04 = (const float4*)c0b;
    float sc = 0.0f, mc = -3.0e38f;
    float sy0 = 0.0f, my0 = -3.0e38f, sy1 = 0.0f, my1 = -3.0e38f;
#pragma unroll
    for (int kb = 0; kb < 4; ++kb) {
      float4 cq = c04[q * 4 + kb];
      float c0a[4] = {cq.x, cq.y, cq.z, cq.w};
#pragma unroll
      for (int i = 0; i < 4; ++i) {
        const int k = 4 * kb + i;
        const float a = attc[k];
        const float pc0 = a * c0a[i], py0 = a * y0[k], py1 = a * y1[k];
        sc += pc0;  mc = fmaxf(mc, pc0);
        sy0 += py0; my0 = fmaxf(my0, py0);
        sy1 += py1; my1 = fmaxf(my1, py1);
      }
    }
    sc = qsum4(sc);   mc = qmax4(mc);
    sy0 = qsum4(sy0); my0 = qmax4(my0);
    sy1 = qsum4(sy1); my1 = qmax4(my1);

    // analytic conv over 32 bins, 8 bins per lane, quad-combined
    const float inv64 = 1.0f / 64.0f;
    const float Mn = sc * inv64, Mx = mc;
    const float dm0 = (sy0 - sc) * inv64, dx0 = my0 - mc;
    const float dm1 = (sy1 - sc) * inv64, dx1 = my1 - mc;
    const float bspr = bsp[0];
    const float2* ws2 = (const float2*)wsmx;
    const float2* wt2 = (const float2*)wtab;
    float maxE = -3.0e38f, minE = 3.0e38f, sv0 = -3.0e38f, sv1 = -3.0e38f;
#pragma unroll
    for (int k = 0; k < 8; ++k) {
      const int b = 8 * q + k;
      float2 ws = ws2[b];
      float acc2v = bspr + Mn * ws.x + Mx * ws.y;
      int k0 = b0 - b + 3;  k0 = ((unsigned)k0 <= 6u) ? k0 : 7;
      int k1 = b1e - b + 3; k1 = ((unsigned)k1 <= 6u) ? k1 : 7;
      float2 w0 = wt2[k0];
      float2 w1v = wt2[k1];
      acc2v += dm0 * w0.x + dx0 * w0.y + dm1 * w1v.x + dx1 * w1v.y;
      const bool o0 = (b == b0), o1 = (b == b1e);
      const bool oc = o0 || o1;
      maxE = fmaxf(maxE, oc ? -3.0e38f : acc2v);
      minE = fminf(minE, oc ?  3.0e38f : acc2v);
      sv0 = o0 ? acc2v : sv0;
      sv1 = o1 ? acc2v : sv1;
    }
    maxE = qmax4(maxE); minE = qmin4(minE);
    sv0 = qmax4(sv0);   sv1 = qmax4(sv1);
    const float sig0 = sgm(sv0);
    const float sig1 = has2 ? sgm(sv1) : sig0;
    const float sE = sgm(maxE), sI = sgm(minE);

    // epilogue: final max over bins, stores
    if (pg < U) {
      float4* ov = (float4*)(out + (size_t)pg * CO + 16 * q);
#pragma unroll
      for (int kb = 0; kb < 4; ++kb) {
        float4 cq = c04[q * 4 + kb];
        float c0a[4] = {cq.x, cq.y, cq.z, cq.w};
        float rr[4];
#pragma unroll
        for (int i = 0; i < 4; ++i) {
          const int k = 4 * kb + i;
          const float c0v = c0a[i];
          const float sel = (c0v >= 0.0f) ? sE : sI;
          const float m = fmaxf(fmaxf(y0[k] * sig0, y1[k] * sig1), c0v * sel);
          rr[i] = attc[k] * m;
        }
        float4 r; r.x = rr[0]; r.y = rr[1]; r.z = rr[2]; r.w = rr[3];
        ov[kb] = r;
      }
      if (q == 0) out[(size_t)U * CO + pg] = has2 ? 1.0f : 0.0f;
    }

    // ---- next trip's vbuf fill must have landed before reuse
    drain_vm();
  }
}

extern "C" void kernel_launch(void* const* d_in, const int* in_sizes, int n_in,
                              void* d_out, int out_size, void* d_ws, size_t ws_size,
                              hipStream_t stream) {
  const float* vf      = (const float*)d_in[0];
  const int*   vcoord  = (const int*)d_in[1];
  // d_in[2] = unq_coords (unused: identity)
  const int*   unq_inv = (const int*)d_in[3];
  const int*   unq_cnt = (const int*)d_in[4];
  const float* W1  = (const float*)d_in[5];
  const float* b1  = (const float*)d_in[6];
  const float* W2  = (const float*)d_in[7];
  const float* b2  = (const float*)d_in[8];
  const float* Wc1 = (const float*)d_in[9];
  const float* bc1 = (const float*)d_in[10];
  const float* Wc2 = (const float*)d_in[11];
  const float* bc2 = (const float*)d_in[12];
  const float* Wsp = (const float*)d_in[13];
  const float* bsp = (const float*)d_in[14];

  const int N = in_sizes[3];   // voxels
  const int U = in_sizes[4];   // pillars

  float* pvox = (float*)d_ws;  // 2U records x 32B (6.4 MB @ U=100k)

  pack_kernel<<<(N + 255) / 256, 256, 0, stream>>>(vf, vcoord, unq_inv, pvox, N);

  // resident blocks/CU from compiled resources (host-side query, capture-safe).
  // Occupancy steps at 64/128/256 VGPR (HW granule).
  static int blocksPerCU = 0;
  if (blocksPerCU == 0) {
    hipFuncAttributes a{};
    blocksPerCU = 4;
    if (hipFuncGetAttributes(&a, (const void*)cbam_kernel) == hipSuccess) {
      int byV = 4;
      if (a.numRegs > 0) {
        if (a.numRegs <= 64) byV = 8;
        else if (a.numRegs <= 128) byV = 4;
        else byV = 2;
      }
      int byL = (a.sharedSizeBytes > 0)
                    ? (int)(163840 / (int)a.sharedSizeBytes) : 4;  // blocks/CU
      int m = byV < byL ? byV : byL;
      if (m < 1) m = 1;
      if (m > 8) m = 8;
      blocksPerCU = m;
    }
  }

  const int ngroups = (U + 15) / 16;      // 16 pillars per wave-trip
  int blocks = 256 * blocksPerCU;         // exactly-resident persistent grid
  const int maxBlocks = (ngroups + 3) / 4;
  if (blocks > maxBlocks) blocks = maxBlocks;
  const int totalWaves = blocks * 4;
  cbam_kernel<<<blocks, 256, 0, stream>>>(
      pvox, unq_cnt, W1, b1, W2, b2, Wc1, bc1, Wc2, bc2, Wsp, bsp,
      (float*)d_out, U, ngroups, totalWaves);
}

// Round 11
// 125.243 us; speedup vs baseline: 1.1078x; 1.0018x over previous
//
#include <hip/hip_runtime.h>
#include <math.h>

// CBAM pillar kernel for MI355X (gfx950) — round 26.
//
// R25 (3-term split + MFMA chMLP-l2): cbam ~38.5us (out of rocprof top-5;
// bench 125.5 with ~87us fixed harness fill/pack overhead).  absmax 0.0625
// — precision budget spent, no more quantization cuts.
// New accounting: ~75KB LDS traffic per wave-trip x 16 waves/CU ≈ 70-85%
// LDS-pipe occupancy per trip-period -> LDS bandwidth is now co-dominant
// with VALU (45%).  VGPR 104 of 128 budget -> spend registers on traffic:
// R26:
//  - wc1f B-frags cached in registers (16 VGPR, loaded pre-loop, no
//    launder -> LICM keeps resident): -8KB/trip LDS + -8 instr.
//  - next-trip unq_cnt prefetched into a register: hides the per-trip
//    global metadata latency.
// Everything else identical to R25.

#define CO 64

typedef __attribute__((ext_vector_type(8))) short s16x8;
typedef __attribute__((ext_vector_type(4))) float f32x4;
union ABu { uint4 u4; s16x8 s; };

__device__ __forceinline__ float sgm(float x) {
  return 1.0f / (1.0f + __expf(-x));
}
template <int PAT>
__device__ __forceinline__ float qadd(float s) {
  int t = __builtin_amdgcn_update_dpp(0, __builtin_bit_cast(int, s),
                                      PAT, 0xf, 0xf, true);
  return s + __builtin_bit_cast(float, t);
}
template <int PAT>
__device__ __forceinline__ float qmaxd(float m) {
  int t = __builtin_amdgcn_update_dpp(__builtin_bit_cast(int, m),
                                      __builtin_bit_cast(int, m),
                                      PAT, 0xf, 0xf, false);
  return fmaxf(m, __builtin_bit_cast(float, t));
}
template <int PAT>
__device__ __forceinline__ float qmind(float m) {
  int t = __builtin_amdgcn_update_dpp(__builtin_bit_cast(int, m),
                                      __builtin_bit_cast(int, m),
                                      PAT, 0xf, 0xf, false);
  return fminf(m, __builtin_bit_cast(float, t));
}
// full exchange within each 4-lane quad: 0xB1=[1,0,3,2], 0x4E=[2,3,0,1]
__device__ __forceinline__ float qsum4(float s) { return qadd<0x4E>(qadd<0xB1>(s)); }
__device__ __forceinline__ float qmax4(float m) { return qmaxd<0x4E>(qmaxd<0xB1>(m)); }
__device__ __forceinline__ float qmin4(float m) { return qmind<0x4E>(qmind<0xB1>(m)); }
__device__ __forceinline__ void drain_lds() {
  __builtin_amdgcn_wave_barrier();
  __builtin_amdgcn_s_waitcnt(0xC07F);   // lgkmcnt(0)
  __builtin_amdgcn_wave_barrier();
}
__device__ __forceinline__ void drain_vm() {
  __builtin_amdgcn_wave_barrier();
  __builtin_amdgcn_s_waitcnt(0x0F70);   // vmcnt(0)
  __builtin_amdgcn_wave_barrier();
}

// RTN bf16 (RNE) via bit-twiddle — used in once-per-block staging.
__device__ __forceinline__ uint rtn16(float f) {
  uint u = __builtin_bit_cast(uint, f);
  return u + 0x7fffu + ((u >> 16) & 1u);
}
// packed RNE f32->bf16x2 (hw op); lo16 = bf16(a), hi16 = bf16(b)
__device__ __forceinline__ uint cvtpk(float a, float b) {
  uint r;
  asm("v_cvt_pk_bf16_f32 %0, %1, %2" : "=v"(r) : "v"(a), "v"(b));
  return r;
}
// e[8] (k-order) -> hi/lo bf16 fragments; u32[p] packs (e[2p], e[2p+1]).
__device__ __forceinline__ void mk_frag(const float* e, ABu& hi, ABu& lo) {
  uint h[4], l[4];
#pragma unroll
  for (int p = 0; p < 4; ++p) {
    h[p] = cvtpk(e[2 * p], e[2 * p + 1]);
    float d0 = e[2 * p]     - __builtin_bit_cast(float, h[p] << 16);
    float d1 = e[2 * p + 1] - __builtin_bit_cast(float, h[p] & 0xffff0000u);
    l[p] = cvtpk(d0, d1);
  }
  hi.u4 = make_uint4(h[0], h[1], h[2], h[3]);
  lo.u4 = make_uint4(l[0], l[1], l[2], l[3]);
}

// per-voxel: pvox[2p+slot] = {vf[5], bits(bin), 0, 0}  (32B records)
__global__ __launch_bounds__(256) void pack_kernel(
    const float* __restrict__ vf, const int* __restrict__ vcoord,
    const int* __restrict__ unq_inv, float* __restrict__ pvox, int n) {
  int i = blockIdx.x * blockDim.x + threadIdx.x;
  if (i >= n) return;
  int p = unq_inv[i];
  int slot = (i > 0 && unq_inv[i - 1] == p) ? 1 : 0;
  float* dst = pvox + 8 * (size_t)(2 * p + slot);
#pragma unroll
  for (int k = 0; k < 5; ++k) dst[k] = vf[5 * i + k];
  ((int*)dst)[5] = vcoord[4 * i + 1];
}

__global__ __launch_bounds__(256) void cbam_kernel(
    const float* __restrict__ pvox, const int* __restrict__ unq_cnt,
    const float* __restrict__ W1, const float* __restrict__ b1,
    const float* __restrict__ W2, const float* __restrict__ b2,
    const float* __restrict__ Wc1, const float* __restrict__ bc1,
    const float* __restrict__ Wc2, const float* __restrict__ bc2,
    const float* __restrict__ Wsp, const float* __restrict__ bsp,
    float* __restrict__ out, int U, int ngroups, int totalWaves) {
  __shared__ __align__(16) uint4 w2fh[256], w2fl[256];   // W2 bf16 B-frags
  __shared__ __align__(16) uint4 wc1fh[128], wc1fl[128]; // Wc1 bf16 B-frags
  __shared__ __align__(16) uint4 wc2fh[128], wc2fl[128]; // [Wc2;Wc2] B-frags
                                                         // (half-width: g&1)
  __shared__ __align__(16) float w1b[160], b1b[32];
  __shared__ __align__(16) float c0b[64], b2b[64], bc2b[64], bc1b[16];
  __shared__ __align__(16) float wsmx[64];    // float2[32] window sums
  __shared__ __align__(16) float wtab[16];    // float2[8] taps, [7]={0,0}
  __shared__ __align__(16) float vbuf[4][256];    // per-wave voxel block (1KB)
  __shared__ __align__(16) float ybuf[4][1088];   // per-wave scratch (4352B)

  const int tid = threadIdx.x;

  // ---- stage weights (once per block; persistent blocks)
  {  // W2 -> bf16 hi/lo B-fragments: tile nt=tid>>6, lane l=tid&63
    const int nt = tid >> 6, l = tid & 63, gg = l >> 4, cc = l & 15;
    uint hu[4], lu[4];
#pragma unroll
    for (int p = 0; p < 4; ++p) {
      float f0 = W2[(8 * gg + 2 * p)     * 64 + 16 * nt + cc];
      float f1 = W2[(8 * gg + 2 * p + 1) * 64 + 16 * nt + cc];
      uint r0 = rtn16(f0), r1 = rtn16(f1);
      hu[p] = (r0 >> 16) | (r1 & 0xffff0000u);
      float d0 = f0 - __builtin_bit_cast(float, r0 & 0xffff0000u);
      float d1 = f1 - __builtin_bit_cast(float, r1 & 0xffff0000u);
      uint s0 = rtn16(d0), s1 = rtn16(d1);
      lu[p] = (s0 >> 16) | (s1 & 0xffff0000u);
    }
    w2fh[tid] = make_uint4(hu[0], hu[1], hu[2], hu[3]);
    w2fl[tid] = make_uint4(lu[0], lu[1], lu[2], lu[3]);
  }
  if (tid < 128) {  // Wc1 -> bf16 hi/lo B-frags, 2 k-steps (ks=tid>>6)
    const int ks = tid >> 6, l = tid & 63, gg = l >> 4, cc = l & 15;
    uint hu[4], lu[4];
#pragma unroll
    for (int p = 0; p < 4; ++p) {
      float f0 = Wc1[(32 * ks + 8 * gg + 2 * p)     * 16 + cc];
      float f1 = Wc1[(32 * ks + 8 * gg + 2 * p + 1) * 16 + cc];
      uint r0 = rtn16(f0), r1 = rtn16(f1);
      hu[p] = (r0 >> 16) | (r1 & 0xffff0000u);
      float d0 = f0 - __builtin_bit_cast(float, r0 & 0xffff0000u);
      float d1 = f1 - __builtin_bit_cast(float, r1 & 0xffff0000u);
      uint s0 = rtn16(d0), s1 = rtn16(d1);
      lu[p] = (s0 >> 16) | (s1 & 0xffff0000u);
    }
    wc1fh[tid] = make_uint4(hu[0], hu[1], hu[2], hu[3]);
    wc1fl[tid] = make_uint4(lu[0], lu[1], lu[2], lu[3]);
  }
  if (tid < 128) {  // [Wc2;Wc2] B-frags, half-width: idx = nt*32 + g01*16 + cc
    const int nt = tid >> 5, r5 = tid & 31, g01 = r5 >> 4, cc = r5 & 15;
    uint hu[4], lu[4];
#pragma unroll
    for (int p = 0; p < 4; ++p) {
      float f0 = Wc2[(8 * g01 + 2 * p)     * 64 + 16 * nt + cc];
      float f1 = Wc2[(8 * g01 + 2 * p + 1) * 64 + 16 * nt + cc];
      uint r0 = rtn16(f0), r1 = rtn16(f1);
      hu[p] = (r0 >> 16) | (r1 & 0xffff0000u);
      float d0 = f0 - __builtin_bit_cast(float, r0 & 0xffff0000u);
      float d1 = f1 - __builtin_bit_cast(float, r1 & 0xffff0000u);
      uint s0 = rtn16(d0), s1 = rtn16(d1);
      lu[p] = (s0 >> 16) | (s1 & 0xffff0000u);
    }
    wc2fh[tid] = make_uint4(hu[0], hu[1], hu[2], hu[3]);
    wc2fl[tid] = make_uint4(lu[0], lu[1], lu[2], lu[3]);
  }
  if (tid < 160) w1b[tid] = W1[tid];
  if (tid < 32) b1b[tid] = b1[tid];
  if (tid < 64) { b2b[tid] = b2[tid]; bc2b[tid] = bc2[tid]; }
  if (tid < 16) bc1b[tid] = bc1[tid];
  if (tid < 32) {
    float sm = 0.0f, sx = 0.0f;
    for (int k = 0; k < 7; ++k)
      if ((unsigned)(tid + k - 3) < 32u) { sm += Wsp[k]; sx += Wsp[7 + k]; }
    wsmx[2 * tid] = sm; wsmx[2 * tid + 1] = sx;
  }
  if (tid < 8) {
    float a = 0.0f, b = 0.0f;
    if (tid < 7) { a = Wsp[tid]; b = Wsp[7 + tid]; }
    wtab[2 * tid] = a; wtab[2 * tid + 1] = b;
  }
  __syncthreads();
  if (tid < 64) {                      // c0[ch] = b2 + relu(b1) @ W2 (f32)
    float c = b2b[tid];
    for (int j = 0; j < 32; ++j) c += fmaxf(b1b[j], 0.0f) * W2[j * 64 + tid];
    c0b[tid] = c;
  }
  __syncthreads();

  const int wv = tid >> 6, lane = tid & 63;
  int grp = blockIdx.x * 4 + wv;       // static grid-stride schedule
  if (grp >= ngroups) return;          // all __syncthreads are above

  float* const vb = vbuf[wv];
  float4* const vb4 = (float4*)vb;
  float* const scr = ybuf[wv];         // per-wave scratch
  float4* const yb4 = (float4*)scr;    // y-transpose view (pillar stride 9 f4)
  float2* const yb2 = (float2*)scr;    // pillar stride 18 float2

  const int c16 = lane & 15, g = lane >> 4;   // MFMA lane roles
  const int q = lane & 3, pp = lane >> 2;     // post-processing roles
  const float4* pv4 = (const float4*)pvox;
  const int f4max = 4 * U - 1;         // pvox has 4U float4 entries

  // ---- wc1 B-frags cached in registers (loop-invariant, no launder)
  ABu wc1hr[2], wc1lr[2];
#pragma unroll
  for (int ks = 0; ks < 2; ++ks) {
    wc1hr[ks].u4 = wc1fh[ks * 64 + lane];
    wc1lr[ks].u4 = wc1fl[ks * 64 + lane];
  }

  // ---- prologue: async-stage trip-0 voxel block; prefetch trip-0 cnt
  {
    int idx = 64 * grp + lane;
    idx = idx < f4max ? idx : f4max;
    __builtin_amdgcn_global_load_lds(
        (const __attribute__((address_space(1))) void*)(pv4 + idx),
        (__attribute__((address_space(3))) void*)vb4, 16, 0, 0);
  }
  int cntv;
  {
    int pg0 = grp * 16 + pp;
    int pc0 = pg0 < U ? pg0 : (U - 1);
    cntv = unq_cnt[pc0];
  }
  drain_vm();

  for (; grp < ngroups; grp += totalWaves) {
    int ofs0 = 0;
    asm volatile("" : "+s"(ofs0));     // keep per-trip LDS frag reads

    const int P0 = grp * 16;           // 16 pillars this trip

    // ---- metadata (cnt prefetched last trip; bins from current vbuf)
    const int pg = P0 + pp;
    const int cnt = cntv;
    const int* vbi = (const int*)vb;
    const int b0 = vbi[(2 * pp) * 8 + 5] & 31;
    const int b1raw = vbi[(2 * pp + 1) * 8 + 5];

    // ---- phase 1: per-lane A-fragments.  lane owns rows c16, c16+16,
    // k-chunk 8g..8g+7.  h = relu(b1 + v @ W1), split bf16 hi/lo (RNE).
    ABu ah0, al0, ah1, al1;
    {
      const float4* vb4c = (const float4*)vb;
      float4 xa = vb4c[2 * c16], xb = vb4c[2 * c16 + 1];
      float4 yc = vb4c[2 * (c16 + 16)], yd = vb4c[2 * (c16 + 16) + 1];
      float va[5] = {xa.x, xa.y, xa.z, xa.w, xb.x};
      float vc[5] = {yc.x, yc.y, yc.z, yc.w, yd.x};
      const float4* w1b4 = (const float4*)w1b;
      const float4* b1b4 = (const float4*)b1b;
      float4 bA = b1b4[ofs0 + 2 * g], bB = b1b4[ofs0 + 2 * g + 1];
      float e0[8] = {bA.x, bA.y, bA.z, bA.w, bB.x, bB.y, bB.z, bB.w};
      float e1[8] = {bA.x, bA.y, bA.z, bA.w, bB.x, bB.y, bB.z, bB.w};
#pragma unroll
      for (int d = 0; d < 5; ++d) {
        float4 w0 = w1b4[ofs0 + d * 8 + 2 * g];
        float4 w1v = w1b4[ofs0 + d * 8 + 2 * g + 1];
        e0[0] += va[d] * w0.x;  e0[1] += va[d] * w0.y;
        e0[2] += va[d] * w0.z;  e0[3] += va[d] * w0.w;
        e0[4] += va[d] * w1v.x; e0[5] += va[d] * w1v.y;
        e0[6] += va[d] * w1v.z; e0[7] += va[d] * w1v.w;
        e1[0] += vc[d] * w0.x;  e1[1] += vc[d] * w0.y;
        e1[2] += vc[d] * w0.z;  e1[3] += vc[d] * w0.w;
        e1[4] += vc[d] * w1v.x; e1[5] += vc[d] * w1v.y;
        e1[6] += vc[d] * w1v.z; e1[7] += vc[d] * w1v.w;
      }
#pragma unroll
      for (int i = 0; i < 8; ++i) {
        e0[i] = fmaxf(e0[i], 0.0f);
        e1[i] = fmaxf(e1[i], 0.0f);
      }
      mk_frag(e0, ah0, al0);
      mk_frag(e1, ah1, al1);
    }
    drain_lds();                        // vbuf reads retired before DMA refill

    // ---- vbuf dead: issue next trip's fill; prefetch next trip's cnt
    {
      const int nxt = grp + totalWaves;
      if (nxt < ngroups) {
        int nidx = 64 * nxt + lane;
        nidx = nidx < f4max ? nidx : f4max;
        __builtin_amdgcn_global_load_lds(
            (const __attribute__((address_space(1))) void*)(pv4 + nidx),
            (__attribute__((address_space(3))) void*)vb4, 16, 0, 0);
        int pgn = nxt * 16 + pp;
        int pcn = pgn < U ? pgn : (U - 1);
        cntv = unq_cnt[pcn];
      }
    }

    // ---- layer2 via MFMA (3-term), one 16-ch tile at a time through scr.
    float y0[16], y1[16];
#pragma unroll
    for (int nt = 0; nt < 4; ++nt) {
      ABu bh, bl;
      bh.u4 = w2fh[ofs0 + nt * 64 + lane];
      bl.u4 = w2fl[ofs0 + nt * 64 + lane];
      f32x4 acc[2];
      acc[0] = 0; acc[1] = 0;
      acc[0] = __builtin_amdgcn_mfma_f32_16x16x32_bf16(ah0.s, bh.s, acc[0], 0, 0, 0);
      acc[0] = __builtin_amdgcn_mfma_f32_16x16x32_bf16(al0.s, bh.s, acc[0], 0, 0, 0);
      acc[0] = __builtin_amdgcn_mfma_f32_16x16x32_bf16(ah0.s, bl.s, acc[0], 0, 0, 0);
      acc[1] = __builtin_amdgcn_mfma_f32_16x16x32_bf16(ah1.s, bh.s, acc[1], 0, 0, 0);
      acc[1] = __builtin_amdgcn_mfma_f32_16x16x32_bf16(al1.s, bh.s, acc[1], 0, 0, 0);
      acc[1] = __builtin_amdgcn_mfma_f32_16x16x32_bf16(ah1.s, bl.s, acc[1], 0, 0, 0);
      // C layout: col=lane&15 (=ch in tile), row=4g+reg; reg pairs (0,1)/
      // (2,3) are the voxel pairs of pillars 8mt+2g / 8mt+2g+1.  +b2 here.
      const float b2v = b2b[16 * nt + c16];
#pragma unroll
      for (int mt = 0; mt < 2; ++mt)
#pragma unroll
        for (int rp = 0; rp < 2; ++rp) {
          const int p = 8 * mt + 2 * g + rp;
          float2 v2;
          v2.x = acc[mt][2 * rp]     + b2v;
          v2.y = acc[mt][2 * rp + 1] + b2v;
          yb2[p * 18 + c16] = v2;
        }
      if (q == nt) {                    // lanes whose 16 ch are this tile
#pragma unroll
        for (int kk = 0; kk < 8; ++kk) {
          float4 t = yb4[pp * 9 + kk];
          y0[2 * kk]     = t.x; y1[2 * kk]     = t.y;
          y0[2 * kk + 1] = t.z; y1[2 * kk + 1] = t.w;
        }
      }
    }

    const bool has2 = (cnt >= 2);
    const int b1e = has2 ? (b1raw & 31) : 64;
#pragma unroll
    for (int k = 0; k < 16; ++k) y1[k] = has2 ? y1[k] : y0[k];

    // ---- chMLP l1 via MFMA (3-term): Ga = Sa@Wc1, Gm = Sm@Wc1.
    // scr sequentially reused: S_avg -> frags -> S_max -> frags.
    f32x4 accA = 0, accM = 0;
    {
      const float kf = has2 ? 30.0f : 31.0f;     // 32 - nocc
      const float inv32 = 1.0f / 32.0f;
      const float4* c04 = (const float4*)c0b;
      // stage avg stats: S[p=pp][ch 16q+..] (stride 68 floats)
#pragma unroll
      for (int kb = 0; kb < 4; ++kb) {
        float4 cq = c04[q * 4 + kb];
        float4 t;
        t.x = fmaf(cq.x, kf, y0[4 * kb + 0] + (has2 ? y1[4 * kb + 0] : 0.0f)) * inv32;
        t.y = fmaf(cq.y, kf, y0[4 * kb + 1] + (has2 ? y1[4 * kb + 1] : 0.0f)) * inv32;
        t.z = fmaf(cq.z, kf, y0[4 * kb + 2] + (has2 ? y1[4 * kb + 2] : 0.0f)) * inv32;
        t.w = fmaf(cq.w, kf, y0[4 * kb + 3] + (has2 ? y1[4 * kb + 3] : 0.0f)) * inv32;
        *((float4*)(scr + pp * 68 + 16 * q) + kb) = t;
      }
      ABu ah[2], al[2];
#pragma unroll
      for (int ks = 0; ks < 2; ++ks) {
        const float4* s4 = (const float4*)(scr + c16 * 68 + 32 * ks + 8 * g);
        float4 p0 = s4[0], p1 = s4[1];
        float e[8] = {p0.x, p0.y, p0.z, p0.w, p1.x, p1.y, p1.z, p1.w};
        mk_frag(e, ah[ks], al[ks]);
      }
#pragma unroll
      for (int ks = 0; ks < 2; ++ks) {
        accA = __builtin_amdgcn_mfma_f32_16x16x32_bf16(ah[ks].s, wc1hr[ks].s, accA, 0, 0, 0);
        accA = __builtin_amdgcn_mfma_f32_16x16x32_bf16(al[ks].s, wc1hr[ks].s, accA, 0, 0, 0);
        accA = __builtin_amdgcn_mfma_f32_16x16x32_bf16(ah[ks].s, wc1lr[ks].s, accA, 0, 0, 0);
      }
      // stage max stats over the same buffer (in-order DS per wave)
#pragma unroll
      for (int kb = 0; kb < 4; ++kb) {
        float4 cq = c04[q * 4 + kb];
        float4 t;
        t.x = fmaxf(fmaxf(y0[4 * kb + 0], y1[4 * kb + 0]), cq.x);
        t.y = fmaxf(fmaxf(y0[4 * kb + 1], y1[4 * kb + 1]), cq.y);
        t.z = fmaxf(fmaxf(y0[4 * kb + 2], y1[4 * kb + 2]), cq.z);
        t.w = fmaxf(fmaxf(y0[4 * kb + 3], y1[4 * kb + 3]), cq.w);
        *((float4*)(scr + pp * 68 + 16 * q) + kb) = t;
      }
#pragma unroll
      for (int ks = 0; ks < 2; ++ks) {
        const float4* s4 = (const float4*)(scr + c16 * 68 + 32 * ks + 8 * g);
        float4 p0 = s4[0], p1 = s4[1];
        float e[8] = {p0.x, p0.y, p0.z, p0.w, p1.x, p1.y, p1.z, p1.w};
        mk_frag(e, ah[ks], al[ks]);
      }
#pragma unroll
      for (int ks = 0; ks < 2; ++ks) {
        accM = __builtin_amdgcn_mfma_f32_16x16x32_bf16(ah[ks].s, wc1hr[ks].s, accM, 0, 0, 0);
        accM = __builtin_amdgcn_mfma_f32_16x16x32_bf16(al[ks].s, wc1hr[ks].s, accM, 0, 0, 0);
        accM = __builtin_amdgcn_mfma_f32_16x16x32_bf16(ah[ks].s, wc1lr[ks].s, accM, 0, 0, 0);
      }
    }

    // ---- chMLP l2 via MFMA: attpre = [relu(Ga+bc1)|relu(Gm+bc1)] @ [Wc2;Wc2]
    float attc[16];
    {
      // write relu'd pools: row=pillar (stride 36), cols 0..15=ga, 16..31=gm
      const float bc1v = bc1b[c16];
#pragma unroll
      for (int r = 0; r < 4; ++r) {
        scr[(4 * g + r) * 36 + c16]      = fmaxf(accA[r] + bc1v, 0.0f);
        scr[(4 * g + r) * 36 + 16 + c16] = fmaxf(accM[r] + bc1v, 0.0f);
      }
      // A2-frag: lane row=c16 (pillar), k-chunk 8g..8g+7 of the 32-wide row
      ABu a2h, a2l;
      {
        const float4* s4 = (const float4*)(scr + c16 * 36 + 8 * g);
        float4 p0 = s4[0], p1 = s4[1];
        float e[8] = {p0.x, p0.y, p0.z, p0.w, p1.x, p1.y, p1.z, p1.w};
        mk_frag(e, a2h, a2l);
      }
      // 4 output tiles, 3-term; B-frag half-width (g pairs share)
      f32x4 acc2[4];
#pragma unroll
      for (int nt = 0; nt < 4; ++nt) {
        ABu bh, bl;
        bh.u4 = wc2fh[ofs0 + nt * 32 + (g & 1) * 16 + c16];
        bl.u4 = wc2fl[ofs0 + nt * 32 + (g & 1) * 16 + c16];
        f32x4 a = 0;
        a = __builtin_amdgcn_mfma_f32_16x16x32_bf16(a2h.s, bh.s, a, 0, 0, 0);
        a = __builtin_amdgcn_mfma_f32_16x16x32_bf16(a2l.s, bh.s, a, 0, 0, 0);
        a = __builtin_amdgcn_mfma_f32_16x16x32_bf16(a2h.s, bl.s, a, 0, 0, 0);
        acc2[nt] = a;
      }
      // sigmoid in C layout; bounce to (pp,q) layout (stride 68)
#pragma unroll
      for (int nt = 0; nt < 4; ++nt) {
        const float b2c = 2.0f * bc2b[16 * nt + c16];
#pragma unroll
        for (int r = 0; r < 4; ++r)
          scr[(4 * g + r) * 68 + 16 * nt + c16] = sgm(acc2[nt][r] + b2c);
      }
      const float4* a4 = (const float4*)(scr + pp * 68 + 16 * q);
#pragma unroll
      for (int kb = 0; kb < 4; ++kb) {
        float4 t = a4[kb];
        attc[4 * kb] = t.x; attc[4 * kb + 1] = t.y;
        attc[4 * kb + 2] = t.z; attc[4 * kb + 3] = t.w;
      }
    }

    // ---- bin-column partial reductions (products with attc)
    const float4* c04 = (const float4*)c0b;
    float sc = 0.0f, mc = -3.0e38f;
    float sy0 = 0.0f, my0 = -3.0e38f, sy1 = 0.0f, my1 = -3.0e38f;
#pragma unroll
    for (int kb = 0; kb < 4; ++kb) {
      float4 cq = c04[q * 4 + kb];
      float c0a[4] = {cq.x, cq.y, cq.z, cq.w};
#pragma unroll
      for (int i = 0; i < 4; ++i) {
        const int k = 4 * kb + i;
        const float a = attc[k];
        const float pc0 = a * c0a[i], py0 = a * y0[k], py1 = a * y1[k];
        sc += pc0;  mc = fmaxf(mc, pc0);
        sy0 += py0; my0 = fmaxf(my0, py0);
        sy1 += py1; my1 = fmaxf(my1, py1);
      }
    }
    sc = qsum4(sc);   mc = qmax4(mc);
    sy0 = qsum4(sy0); my0 = qmax4(my0);
    sy1 = qsum4(sy1); my1 = qmax4(my1);

    // analytic conv over 32 bins, 8 bins per lane, quad-combined
    const float inv64 = 1.0f / 64.0f;
    const float Mn = sc * inv64, Mx = mc;
    const float dm0 = (sy0 - sc) * inv64, dx0 = my0 - mc;
    const float dm1 = (sy1 - sc) * inv64, dx1 = my1 - mc;
    const float bspr = bsp[0];
    const float2* ws2 = (const float2*)wsmx;
    const float2* wt2 = (const float2*)wtab;
    float maxE = -3.0e38f, minE = 3.0e38f, sv0 = -3.0e38f, sv1 = -3.0e38f;
#pragma unroll
    for (int k = 0; k < 8; ++k) {
      const int b = 8 * q + k;
      float2 ws = ws2[b];
      float acc2v = bspr + Mn * ws.x + Mx * ws.y;
      int k0 = b0 - b + 3;  k0 = ((unsigned)k0 <= 6u) ? k0 : 7;
      int k1 = b1e - b + 3; k1 = ((unsigned)k1 <= 6u) ? k1 : 7;
      float2 w0 = wt2[k0];
      float2 w1v = wt2[k1];
      acc2v += dm0 * w0.x + dx0 * w0.y + dm1 * w1v.x + dx1 * w1v.y;
      const bool o0 = (b == b0), o1 = (b == b1e);
      const bool oc = o0 || o1;
      maxE = fmaxf(maxE, oc ? -3.0e38f : acc2v);
      minE = fminf(minE, oc ?  3.0e38f : acc2v);
      sv0 = o0 ? acc2v : sv0;
      sv1 = o1 ? acc2v : sv1;
    }
    maxE = qmax4(maxE); minE = qmin4(minE);
    sv0 = qmax4(sv0);   sv1 = qmax4(sv1);
    const float sig0 = sgm(sv0);
    const float sig1 = has2 ? sgm(sv1) : sig0;
    const float sE = sgm(maxE), sI = sgm(minE);

    // epilogue: final max over bins, stores
    if (pg < U) {
      float4* ov = (float4*)(out + (size_t)pg * CO + 16 * q);
#pragma unroll
      for (int kb = 0; kb < 4; ++kb) {
        float4 cq = c04[q * 4 + kb];
        float c0a[4] = {cq.x, cq.y, cq.z, cq.w};
        float rr[4];
#pragma unroll
        for (int i = 0; i < 4; ++i) {
          const int k = 4 * kb + i;
          const float c0v = c0a[i];
          const float sel = (c0v >= 0.0f) ? sE : sI;
          const float m = fmaxf(fmaxf(y0[k] * sig0, y1[k] * sig1), c0v * sel);
          rr[i] = attc[k] * m;
        }
        float4 r; r.x = rr[0]; r.y = rr[1]; r.z = rr[2]; r.w = rr[3];
        ov[kb] = r;
      }
      if (q == 0) out[(size_t)U * CO + pg] = has2 ? 1.0f : 0.0f;
    }

    // ---- next trip's vbuf fill must have landed before reuse
    drain_vm();
  }
}

extern "C" void kernel_launch(void* const* d_in, const int* in_sizes, int n_in,
                              void* d_out, int out_size, void* d_ws, size_t ws_size,
                              hipStream_t stream) {
  const float* vf      = (const float*)d_in[0];
  const int*   vcoord  = (const int*)d_in[1];
  // d_in[2] = unq_coords (unused: identity)
  const int*   unq_inv = (const int*)d_in[3];
  const int*   unq_cnt = (const int*)d_in[4];
  const float* W1  = (const float*)d_in[5];
  const float* b1  = (const float*)d_in[6];
  const float* W2  = (const float*)d_in[7];
  const float* b2  = (const float*)d_in[8];
  const float* Wc1 = (const float*)d_in[9];
  const float* bc1 = (const float*)d_in[10];
  const float* Wc2 = (const float*)d_in[11];
  const float* bc2 = (const float*)d_in[12];
  const float* Wsp = (const float*)d_in[13];
  const float* bsp = (const float*)d_in[14];

  const int N = in_sizes[3];   // voxels
  const int U = in_sizes[4];   // pillars

  float* pvox = (float*)d_ws;  // 2U records x 32B (6.4 MB @ U=100k)

  pack_kernel<<<(N + 255) / 256, 256, 0, stream>>>(vf, vcoord, unq_inv, pvox, N);

  // resident blocks/CU from compiled resources (host-side query, capture-safe).
  // Occupancy steps at 64/128/256 VGPR (HW granule).
  static int blocksPerCU = 0;
  if (blocksPerCU == 0) {
    hipFuncAttributes a{};
    blocksPerCU = 4;
    if (hipFuncGetAttributes(&a, (const void*)cbam_kernel) == hipSuccess) {
      int byV = 4;
      if (a.numRegs > 0) {
        if (a.numRegs <= 64) byV = 8;
        else if (a.numRegs <= 128) byV = 4;
        else byV = 2;
      }
      int byL = (a.sharedSizeBytes > 0)
                    ? (int)(163840 / (int)a.sharedSizeBytes) : 4;  // blocks/CU
      int m = byV < byL ? byV : byL;
      if (m < 1) m = 1;
      if (m > 8) m = 8;
      blocksPerCU = m;
    }
  }

  const int ngroups = (U + 15) / 16;      // 16 pillars per wave-trip
  int blocks = 256 * blocksPerCU;         // exactly-resident persistent grid
  const int maxBlocks = (ngroups + 3) / 4;
  if (blocks > maxBlocks) blocks = maxBlocks;
  const int totalWaves = blocks * 4;
  cbam_kernel<<<blocks, 256, 0, stream>>>(
      pvox, unq_cnt, W1, b1, W2, b2, Wc1, bc1, Wc2, bc2, Wsp, bsp,
      (float*)d_out, U, ngroups, totalWaves);
}